// Round 6
// baseline (384.612 us; speedup 1.0000x reference)
//
#include <hip/hip_runtime.h>
#include <hip/hip_bf16.h>

#define S_LEN 2048
#define HID 4096
#define NH 32
#define NKV 8
#define HD 128

typedef __attribute__((ext_vector_type(4))) float f32x4;
typedef __attribute__((ext_vector_type(8))) __bf16 bf16x8;
typedef __attribute__((ext_vector_type(8))) unsigned short u16x8;
typedef __attribute__((ext_vector_type(4))) unsigned short u16x4;

static __device__ __forceinline__ unsigned short f2bf(float x) {
  return __builtin_bit_cast(unsigned short, __float2bfloat16(x));
}
static __device__ __forceinline__ float bf2f(unsigned short u) {
  return __builtin_bit_cast(float, (unsigned int)u << 16);
}
static __device__ __forceinline__ void gld16(const unsigned short* g, unsigned short* l) {
  __builtin_amdgcn_global_load_lds(
      (const __attribute__((address_space(1))) unsigned int*)g,
      (__attribute__((address_space(3))) unsigned int*)l, 16, 0, 0);
}

// ---------------- fp32 -> bf16 bulk convert ----------------
__global__ void f2bf_kernel(const float* __restrict__ in, unsigned short* __restrict__ out, int n8) {
  int i = blockIdx.x * 256 + threadIdx.x;
  if (i >= n8) return;
  f32x4 a = ((const f32x4*)in)[(size_t)i * 2];
  f32x4 b = ((const f32x4*)in)[(size_t)i * 2 + 1];
  u16x8 w;
#pragma unroll
  for (int j = 0; j < 4; ++j) {
    w[j] = f2bf(a[j]);
    w[4 + j] = f2bf(b[j]);
  }
  ((u16x8*)out)[(size_t)i] = w;
}

// ---------------- split-K partial reduce: out = p[0] + p[1] (bf16 -> fp32) ----------------
__global__ void reduce2_kernel(const unsigned short* __restrict__ p, float* __restrict__ out, int n8) {
  int i = blockIdx.x * 256 + threadIdx.x;
  if (i >= n8) return;
  u16x8 a = ((const u16x8*)p)[(size_t)i];
  u16x8 b = ((const u16x8*)(p + (size_t)S_LEN * HID))[(size_t)i];
  f32x4 o0, o1;
#pragma unroll
  for (int j = 0; j < 4; ++j) {
    o0[j] = bf2f(a[j]) + bf2f(b[j]);
    o1[j] = bf2f(a[4 + j]) + bf2f(b[4 + j]);
  }
  ((f32x4*)out)[(size_t)i * 2] = o0;
  ((f32x4*)out)[(size_t)i * 2 + 1] = o1;
}

// ---------------- RoPE table ----------------
__global__ void rope_table(float* cs) {
  int idx = blockIdx.x * blockDim.x + threadIdx.x;
  if (idx >= S_LEN * 64) return;
  int d = idx & 63;
  int p = idx >> 6;
  float invf = exp2f(-(float)d * (19.9315685693241741f / 64.0f));  // theta^-d/64
  float ang = (float)p * invf;
  cs[idx] = cosf(ang);
  cs[S_LEN * 64 + idx] = sinf(ang);
}

// ---------------- RoPE apply (in-place, bf16 [head][S][128], x scale) ----------------
__global__ void rope_apply(unsigned short* __restrict__ buf, const float* __restrict__ cs,
                           float scale, int total) {
  int idx = blockIdx.x * blockDim.x + threadIdx.x;
  if (idx >= total) return;  // total = nheads * S * 64
  int d = idx & 63;
  int hp = idx >> 6;
  int pos = hp & (S_LEN - 1);
  size_t base = (size_t)hp * HD;
  float c = cs[pos * 64 + d];
  float s = cs[S_LEN * 64 + pos * 64 + d];
  float x1 = bf2f(buf[base + d]);
  float x2 = bf2f(buf[base + 64 + d]);
  buf[base + d] = f2bf((x1 * c - x2 * s) * scale);
  buf[base + 64 + d] = f2bf((x2 * c + x1 * s) * scale);
}

// ---------------- GEMM: C[2048,N] = A[2048,4096] @ W[N,4096]^T ----------------
// EXACT round-2 structure (852 TF @ 3 blocks/CU): 128x128 tile, BK=32, single
// LDS buffer, global_load_lds(16B), 2 barriers/K-step, simple epilogue.
// dbuf / B-frag remap / RoPE-fused epilogue all REGRESSED (round 3/4).
// MODE 1: fused QKV epilogue -> Qb/Kb (bf16 [head][S][128], +bias), VTb ([n][S], +bias)
// MODE 2: split-K out-projection: grid (16,32,2), z = K-half, bf16 partials
//         at Qb_arg + z*S*HID (MODE 0/1 K-range folds to constants, codegen unchanged)
template <int MODE>
__global__ __launch_bounds__(256) void gemm_nt(
    const unsigned short* __restrict__ A, const unsigned short* __restrict__ W,
    const float* __restrict__ bq, const float* __restrict__ bk, const float* __restrict__ bv,
    unsigned short* __restrict__ Qb, unsigned short* __restrict__ Kb,
    unsigned short* __restrict__ VTb, float* __restrict__ Cout) {
  __shared__ unsigned short As[4096];  // [128 rows][32] linear
  __shared__ unsigned short Bs[4096];
  int lin = blockIdx.x + 16 * blockIdx.y;
  int cpx = (16 * gridDim.y) >> 3;
  int swz = (lin & 7) * cpx + (lin >> 3);
  const int m0 = (swz & 15) * 128;
  const int n0 = (swz >> 4) * 128;
  const int tid = threadIdx.x, lane = tid & 63, wv = tid >> 6;
  const int wr = wv >> 1, wc = wv & 1;
  const int lr = lane & 15, lg = lane >> 4;
  const int srow = lane >> 2, skk = (lane & 3) * 8;

  const unsigned short* Ag0 = A + (size_t)(m0 + wv * 32 + srow) * HID + skk;
  const unsigned short* Ag1 = Ag0 + (size_t)16 * HID;
  const unsigned short* Wg0 = W + (size_t)(n0 + wv * 32 + srow) * HID + skk;
  const unsigned short* Wg1 = Wg0 + (size_t)16 * HID;
  unsigned short* Al0 = As + wv * 1024;  // wave-uniform LDS slice bases
  unsigned short* Al1 = As + wv * 1024 + 512;
  unsigned short* Bl0 = Bs + wv * 1024;
  unsigned short* Bl1 = Bs + wv * 1024 + 512;

  f32x4 acc[4][4] = {};

  int kt0 = 0, kt1 = HID / 32;
  if (MODE == 2) { kt0 = blockIdx.z << 6; kt1 = kt0 + 64; }

  for (int kt = kt0; kt < kt1; ++kt) {
    const int ko = kt * 32;
    gld16(Ag0 + ko, Al0);
    gld16(Ag1 + ko, Al1);
    gld16(Wg0 + ko, Bl0);
    gld16(Wg1 + ko, Bl1);
    __syncthreads();  // drains vmcnt -> tile visible
    bf16x8 af[4], bfr[4];
#pragma unroll
    for (int i = 0; i < 4; ++i)
      af[i] = *(const bf16x8*)&As[(wr * 64 + i * 16 + lr) * 32 + lg * 8];
#pragma unroll
    for (int i = 0; i < 4; ++i)
      bfr[i] = *(const bf16x8*)&Bs[(wc * 64 + i * 16 + lr) * 32 + lg * 8];
#pragma unroll
    for (int mi = 0; mi < 4; ++mi)
#pragma unroll
      for (int ni = 0; ni < 4; ++ni)
        acc[mi][ni] = __builtin_amdgcn_mfma_f32_16x16x32_bf16(af[mi], bfr[ni], acc[mi][ni], 0, 0, 0);
    __syncthreads();  // reads done -> next stage may overwrite
  }

  if (MODE == 0) {
#pragma unroll
    for (int mi = 0; mi < 4; ++mi) {
      int row = m0 + wr * 64 + mi * 16 + lg * 4;
#pragma unroll
      for (int ni = 0; ni < 4; ++ni) {
        int col = n0 + wc * 64 + ni * 16 + lr;
#pragma unroll
        for (int j = 0; j < 4; ++j)
          Cout[(size_t)(row + j) * HID + col] = acc[mi][ni][j];
      }
    }
  } else if (MODE == 2) {
    unsigned short* P = Qb + (size_t)blockIdx.z * ((size_t)S_LEN * HID);
#pragma unroll
    for (int mi = 0; mi < 4; ++mi) {
      int row = m0 + wr * 64 + mi * 16 + lg * 4;
#pragma unroll
      for (int ni = 0; ni < 4; ++ni) {
        int col = n0 + wc * 64 + ni * 16 + lr;
#pragma unroll
        for (int j = 0; j < 4; ++j)
          P[(size_t)(row + j) * HID + col] = f2bf(acc[mi][ni][j]);
      }
    }
  } else {
    unsigned short* obuf;
    const float* bptr;
    int cbase;
    bool transp = false;
    if (n0 < 4096) { obuf = Qb; bptr = bq; cbase = n0; }
    else if (n0 < 5120) { obuf = Kb; bptr = bk; cbase = n0 - 4096; }
    else { obuf = VTb; bptr = bv; cbase = n0 - 5120; transp = true; }
#pragma unroll
    for (int ni = 0; ni < 4; ++ni) {
      int c = cbase + wc * 64 + ni * 16 + lr;
      float bb = bptr[c];
      if (!transp) {
        int head = c >> 7, d = c & 127;
#pragma unroll
        for (int mi = 0; mi < 4; ++mi) {
          int row = m0 + wr * 64 + mi * 16 + lg * 4;
#pragma unroll
          for (int j = 0; j < 4; ++j)
            obuf[((size_t)head * S_LEN + row + j) * HD + d] = f2bf(acc[mi][ni][j] + bb);
        }
      } else {
#pragma unroll
        for (int mi = 0; mi < 4; ++mi) {
          int row = m0 + wr * 64 + mi * 16 + lg * 4;
          u16x4 pk;
#pragma unroll
          for (int j = 0; j < 4; ++j) pk[j] = f2bf(acc[mi][ni][j] + bb);
          *(u16x4*)&obuf[(size_t)c * S_LEN + row] = pk;
        }
      }
    }
  }
}

// ---------------- Flash attention ----------------
// grid (8, 32): 256 blocks, 8 waves, QBLK=128 (16 rows/wave), KVBLK=64.
// Block p handles q-tiles p and 15-p (34 KV tiles each -> balanced).
// Q pre-scaled (in rope_apply); defer-max (T13); reg prefetch (T14).
__global__ __launch_bounds__(512) void attn_fwd(const unsigned short* __restrict__ Qb,
                                                const unsigned short* __restrict__ Kb,
                                                const unsigned short* __restrict__ VTb,
                                                unsigned short* __restrict__ Ob) {
  __shared__ unsigned short Kl[64][136];
  __shared__ unsigned short Vt[128][72];
  __shared__ unsigned short Pl[8][16][72];
  int lin = blockIdx.x + 8 * blockIdx.y;
  int swz = (lin & 7) * 32 + (lin >> 3);  // each XCD owns 4 q-heads = 1 kv-head
  const int pair = swz & 7;
  const int h = swz >> 3;
  const int kh = h >> 2;
  const int tid = threadIdx.x, lane = tid & 63, wv = tid >> 6;
  const int lr = lane & 15, lg = lane >> 4;
  const int krow = tid >> 4, koff = (tid & 15) * 8;   // K rows krow, krow+32
  const int vrow = tid >> 3, voff = (tid & 7) * 8;    // V rows vrow, vrow+64
  const unsigned short* Kbase = Kb + (size_t)kh * S_LEN * HD;
  const unsigned short* Vbase = VTb + (size_t)kh * HD * S_LEN;

  for (int half = 0; half < 2; ++half) {
    const int qt = half ? 15 - pair : pair;
    const int q0 = qt * 128;
    const int nt = 2 * qt + 2;
    bf16x8 qf[4];
    {
      const unsigned short* qp = Qb + ((size_t)h * S_LEN + q0 + wv * 16 + lr) * HD + lg * 8;
#pragma unroll
      for (int s = 0; s < 4; ++s) qf[s] = *(const bf16x8*)(qp + s * 32);
    }
    f32x4 o[8];
#pragma unroll
    for (int i = 0; i < 8; ++i) o[i] = f32x4{0.f, 0.f, 0.f, 0.f};
    float mrow[4] = {-1e30f, -1e30f, -1e30f, -1e30f};
    float lrow[4] = {0.f, 0.f, 0.f, 0.f};

    u16x8 kreg[2], vreg[2];
    {
      const unsigned short* kp = Kbase + (size_t)krow * HD + koff;
      const unsigned short* vp = Vbase + (size_t)vrow * S_LEN + voff;
      kreg[0] = *(const u16x8*)kp;
      kreg[1] = *(const u16x8*)(kp + (size_t)32 * HD);
      vreg[0] = *(const u16x8*)vp;
      vreg[1] = *(const u16x8*)(vp + (size_t)64 * S_LEN);
    }
    __syncthreads();  // prior half's LDS readers done
    *(u16x8*)&Kl[krow][koff] = kreg[0];
    *(u16x8*)&Kl[krow + 32][koff] = kreg[1];
    *(u16x8*)&Vt[vrow][voff] = vreg[0];
    *(u16x8*)&Vt[vrow + 64][voff] = vreg[1];
    __syncthreads();

    for (int t = 0; t < nt; ++t) {
      if (t + 1 < nt) {  // T14: prefetch next tile into regs
        const unsigned short* kp = Kbase + ((size_t)(t + 1) * 64 + krow) * HD + koff;
        const unsigned short* vp = Vbase + (size_t)vrow * S_LEN + (t + 1) * 64 + voff;
        kreg[0] = *(const u16x8*)kp;
        kreg[1] = *(const u16x8*)(kp + (size_t)32 * HD);
        vreg[0] = *(const u16x8*)vp;
        vreg[1] = *(const u16x8*)(vp + (size_t)64 * S_LEN);
      }
      const int c0 = t * 64;
      const bool active = (c0 <= q0 + wv * 16 + 15);  // wave-uniform: skip fully-masked
      if (active) {
        f32x4 sf[4];
        __builtin_amdgcn_s_setprio(1);
#pragma unroll
        for (int c = 0; c < 4; ++c) {
          f32x4 s = {0.f, 0.f, 0.f, 0.f};
#pragma unroll
          for (int ss = 0; ss < 4; ++ss) {
            bf16x8 kf = *(const bf16x8*)&Kl[c * 16 + lr][ss * 32 + lg * 8];
            s = __builtin_amdgcn_mfma_f32_16x16x32_bf16(qf[ss], kf, s, 0, 0, 0);
          }
          sf[c] = s;
        }
        __builtin_amdgcn_s_setprio(0);

        if (t >= 2 * qt) {  // diagonal tiles only
#pragma unroll
          for (int c = 0; c < 4; ++c)
#pragma unroll
            for (int j = 0; j < 4; ++j)
              if ((c0 + c * 16 + lr) > (q0 + wv * 16 + lg * 4 + j)) sf[c][j] = -1e30f;
        }
        float tmax[4] = {-1e30f, -1e30f, -1e30f, -1e30f};
#pragma unroll
        for (int c = 0; c < 4; ++c)
#pragma unroll
          for (int j = 0; j < 4; ++j) tmax[j] = fmaxf(tmax[j], sf[c][j]);
#pragma unroll
        for (int dlt = 1; dlt < 16; dlt <<= 1)
#pragma unroll
          for (int j = 0; j < 4; ++j)
            tmax[j] = fmaxf(tmax[j], __shfl_xor(tmax[j], dlt, 64));

        // T13 defer-max: only rescale when max grows materially
        bool need = (tmax[0] > mrow[0] + 8.f) || (tmax[1] > mrow[1] + 8.f) ||
                    (tmax[2] > mrow[2] + 8.f) || (tmax[3] > mrow[3] + 8.f);
        if (__any(need)) {
          float alpha[4];
#pragma unroll
          for (int j = 0; j < 4; ++j) {
            float mn = fmaxf(mrow[j], tmax[j]);
            alpha[j] = exp2f(mrow[j] - mn);
            mrow[j] = mn;
          }
#pragma unroll
          for (int f = 0; f < 8; ++f)
#pragma unroll
            for (int j = 0; j < 4; ++j) o[f][j] *= alpha[j];
#pragma unroll
          for (int j = 0; j < 4; ++j) lrow[j] *= alpha[j];
        }
        float tsum[4] = {0.f, 0.f, 0.f, 0.f};
#pragma unroll
        for (int c = 0; c < 4; ++c)
#pragma unroll
          for (int j = 0; j < 4; ++j) {
            float pv = exp2f(sf[c][j] - mrow[j]);
            tsum[j] += pv;
            Pl[wv][lg * 4 + j][(c * 16 + lr) ^ ((lg & 2) << 2)] = f2bf(pv);
          }
#pragma unroll
        for (int dlt = 1; dlt < 16; dlt <<= 1)
#pragma unroll
          for (int j = 0; j < 4; ++j) tsum[j] += __shfl_xor(tsum[j], dlt, 64);
#pragma unroll
        for (int j = 0; j < 4; ++j) lrow[j] += tsum[j];

        // PV
        __builtin_amdgcn_s_setprio(1);
#pragma unroll
        for (int ks = 0; ks < 2; ++ks) {
          bf16x8 pa = *(const bf16x8*)&Pl[wv][lr][(ks * 32 + lg * 8) ^ (lr & 8)];
#pragma unroll
          for (int df = 0; df < 8; ++df) {
            bf16x8 vb = *(const bf16x8*)&Vt[df * 16 + lr][ks * 32 + lg * 8];
            o[df] = __builtin_amdgcn_mfma_f32_16x16x32_bf16(pa, vb, o[df], 0, 0, 0);
          }
        }
        __builtin_amdgcn_s_setprio(0);
      }

      if (t + 1 < nt) {
        __syncthreads();  // all waves done reading current tile
        *(u16x8*)&Kl[krow][koff] = kreg[0];
        *(u16x8*)&Kl[krow + 32][koff] = kreg[1];
        *(u16x8*)&Vt[vrow][voff] = vreg[0];
        *(u16x8*)&Vt[vrow + 64][voff] = vreg[1];
        __syncthreads();
      }
    }

#pragma unroll
    for (int j = 0; j < 4; ++j) {
      float inv = 1.0f / lrow[j];
      int row = q0 + wv * 16 + lg * 4 + j;
#pragma unroll
      for (int df = 0; df < 8; ++df)
        Ob[(size_t)row * (NH * HD) + h * HD + df * 16 + lr] = f2bf(o[df][j] * inv);
    }
  }
}

// ---------------- launch ----------------
extern "C" void kernel_launch(void* const* d_in, const int* in_sizes, int n_in,
                              void* d_out, int out_size, void* d_ws, size_t ws_size,
                              hipStream_t stream) {
  const float* hidden = (const float*)d_in[0];
  const float* wq = (const float*)d_in[1];
  const float* bq = (const float*)d_in[2];
  const float* wk = (const float*)d_in[3];
  const float* bk = (const float*)d_in[4];
  const float* wv = (const float*)d_in[5];
  const float* bv = (const float*)d_in[6];
  const float* wo = (const float*)d_in[7];
  float* out = (float*)d_out;

  char* p = (char*)d_ws;
  float* cs = (float*)p;                      p += (size_t)1 << 20;
  unsigned short* hb = (unsigned short*)p;    p += (size_t)16 << 20;  // hidden bf16; REUSED as split-K partial 0
  unsigned short* Qb = (unsigned short*)p;    p += (size_t)16 << 20;  // Q; REUSED as split-K partial 1
  unsigned short* Kbuf = (unsigned short*)p;  p += (size_t)4 << 20;
  unsigned short* VTb = (unsigned short*)p;   p += (size_t)4 << 20;
  unsigned short* attno = (unsigned short*)p; p += (size_t)16 << 20;
  unsigned short* wbuf = (unsigned short*)p;  // 48 MB reused (qkv weights, then wo)

  const float QSC = 0.08838834764831845f * 1.44269504088896340f;  // 1/sqrt(128)*log2e

  hipLaunchKernelGGL(rope_table, dim3(512), dim3(256), 0, stream, cs);
  hipLaunchKernelGGL(f2bf_kernel, dim3(4096), dim3(256), 0, stream, hidden, hb, S_LEN * HID / 8);
  hipLaunchKernelGGL(f2bf_kernel, dim3(8192), dim3(256), 0, stream, wq, wbuf, 4096 * HID / 8);
  hipLaunchKernelGGL(f2bf_kernel, dim3(2048), dim3(256), 0, stream, wk, wbuf + (size_t)4096 * HID, 1024 * HID / 8);
  hipLaunchKernelGGL(f2bf_kernel, dim3(2048), dim3(256), 0, stream, wv, wbuf + (size_t)5120 * HID, 1024 * HID / 8);
  hipLaunchKernelGGL((gemm_nt<1>), dim3(16, 48), dim3(256), 0, stream,
                     hb, wbuf, bq, bk, bv, Qb, Kbuf, VTb, (float*)nullptr);
  hipLaunchKernelGGL(rope_apply, dim3(16384), dim3(256), 0, stream, Qb, cs, QSC, NH * S_LEN * 64);
  hipLaunchKernelGGL(rope_apply, dim3(4096), dim3(256), 0, stream, Kbuf, cs, 1.0f, NKV * S_LEN * 64);
  hipLaunchKernelGGL(attn_fwd, dim3(8, 32), dim3(512), 0, stream, Qb, Kbuf, VTb, attno);
  hipLaunchKernelGGL(f2bf_kernel, dim3(8192), dim3(256), 0, stream, wo, wbuf, 4096 * HID / 8);
  // split-K=2 out-projection: partials into hb (z=0) and Qb (z=1), contiguous 32 MB
  hipLaunchKernelGGL((gemm_nt<2>), dim3(16, 32, 2), dim3(256), 0, stream,
                     attno, wbuf, (const float*)nullptr, (const float*)nullptr, (const float*)nullptr,
                     hb, (unsigned short*)nullptr, (unsigned short*)nullptr, (float*)nullptr);
  hipLaunchKernelGGL(reduce2_kernel, dim3(4096), dim3(256), 0, stream, hb, out, S_LEN * HID / 8);
}

// Round 7
// 381.416 us; speedup vs baseline: 1.0084x; 1.0084x over previous
//
#include <hip/hip_runtime.h>
#include <hip/hip_bf16.h>

#define S_LEN 2048
#define HID 4096
#define NH 32
#define NKV 8
#define HD 128

typedef __attribute__((ext_vector_type(4))) float f32x4;
typedef __attribute__((ext_vector_type(8))) __bf16 bf16x8;
typedef __attribute__((ext_vector_type(8))) unsigned short u16x8;
typedef __attribute__((ext_vector_type(4))) unsigned short u16x4;

static __device__ __forceinline__ unsigned short f2bf(float x) {
  return __builtin_bit_cast(unsigned short, __float2bfloat16(x));
}
static __device__ __forceinline__ float bf2f(unsigned short u) {
  return __builtin_bit_cast(float, (unsigned int)u << 16);
}
static __device__ __forceinline__ void gld16(const unsigned short* g, unsigned short* l) {
  __builtin_amdgcn_global_load_lds(
      (const __attribute__((address_space(1))) unsigned int*)g,
      (__attribute__((address_space(3))) unsigned int*)l, 16, 0, 0);
}

// ---------------- fp32 -> bf16 bulk convert ----------------
__global__ void f2bf_kernel(const float* __restrict__ in, unsigned short* __restrict__ out, int n8) {
  int i = blockIdx.x * 256 + threadIdx.x;
  if (i >= n8) return;
  f32x4 a = ((const f32x4*)in)[(size_t)i * 2];
  f32x4 b = ((const f32x4*)in)[(size_t)i * 2 + 1];
  u16x8 w;
#pragma unroll
  for (int j = 0; j < 4; ++j) {
    w[j] = f2bf(a[j]);
    w[4 + j] = f2bf(b[j]);
  }
  ((u16x8*)out)[(size_t)i] = w;
}

// ---------------- RoPE table ----------------
__global__ void rope_table(float* cs) {
  int idx = blockIdx.x * blockDim.x + threadIdx.x;
  if (idx >= S_LEN * 64) return;
  int d = idx & 63;
  int p = idx >> 6;
  float invf = exp2f(-(float)d * (19.9315685693241741f / 64.0f));  // theta^-d/64
  float ang = (float)p * invf;
  cs[idx] = cosf(ang);
  cs[S_LEN * 64 + idx] = sinf(ang);
}

// ---------------- RoPE apply (in-place, bf16 [head][S][128], x scale) ----------------
__global__ void rope_apply(unsigned short* __restrict__ buf, const float* __restrict__ cs,
                           float scale, int total) {
  int idx = blockIdx.x * blockDim.x + threadIdx.x;
  if (idx >= total) return;  // total = nheads * S * 64
  int d = idx & 63;
  int hp = idx >> 6;
  int pos = hp & (S_LEN - 1);
  size_t base = (size_t)hp * HD;
  float c = cs[pos * 64 + d];
  float s = cs[S_LEN * 64 + pos * 64 + d];
  float x1 = bf2f(buf[base + d]);
  float x2 = bf2f(buf[base + 64 + d]);
  buf[base + d] = f2bf((x1 * c - x2 * s) * scale);
  buf[base + 64 + d] = f2bf((x2 * c + x1 * s) * scale);
}

// ---------------- GEMM: C[2048,N] = A[2048,4096] @ W[N,4096]^T ----------------
// Round-2 m97 structure with BK=64: the 64-K step is stored as TWO independent
// [128][32] LDS sub-tiles (identical 64-B row stride / conflict-free ds_read /
// gld16 addressing as the proven BK=32 version) -> one barrier pair per 64 K
// instead of per 32 (halves the per-K drain stalls). LDS 32 KB (not m132's
// 64 KB occupancy cliff). Epilogues identical to round 5.
// MODE 0: Cout fp32 [M][4096], no bias (out-projection)
// MODE 1: fused QKV epilogue -> Qb/Kb (bf16 [head][S][128], +bias), VTb ([n][S], +bias)
template <int MODE>
__global__ __launch_bounds__(256) void gemm_nt(
    const unsigned short* __restrict__ A, const unsigned short* __restrict__ W,
    const float* __restrict__ bq, const float* __restrict__ bk, const float* __restrict__ bv,
    unsigned short* __restrict__ Qb, unsigned short* __restrict__ Kb,
    unsigned short* __restrict__ VTb, float* __restrict__ Cout) {
  __shared__ unsigned short As[2][4096];  // [ksub][128 rows][32 cols]
  __shared__ unsigned short Bs[2][4096];
  int lin = blockIdx.x + 16 * blockIdx.y;
  int cpx = (16 * gridDim.y) >> 3;
  int swz = (lin & 7) * cpx + (lin >> 3);
  const int m0 = (swz & 15) * 128;
  const int n0 = (swz >> 4) * 128;
  const int tid = threadIdx.x, lane = tid & 63, wv = tid >> 6;
  const int wr = wv >> 1, wc = wv & 1;
  const int lr = lane & 15, lg = lane >> 4;
  const int srow = lane >> 2, skk = (lane & 3) * 8;

  const unsigned short* Ag0 = A + (size_t)(m0 + wv * 32 + srow) * HID + skk;
  const unsigned short* Ag1 = Ag0 + (size_t)16 * HID;
  const unsigned short* Wg0 = W + (size_t)(n0 + wv * 32 + srow) * HID + skk;
  const unsigned short* Wg1 = Wg0 + (size_t)16 * HID;
  unsigned short* Al0 = &As[0][wv * 1024];  // wave-uniform LDS slice bases
  unsigned short* Al1 = &As[0][wv * 1024 + 512];
  unsigned short* Al2 = &As[1][wv * 1024];
  unsigned short* Al3 = &As[1][wv * 1024 + 512];
  unsigned short* Bl0 = &Bs[0][wv * 1024];
  unsigned short* Bl1 = &Bs[0][wv * 1024 + 512];
  unsigned short* Bl2 = &Bs[1][wv * 1024];
  unsigned short* Bl3 = &Bs[1][wv * 1024 + 512];

  f32x4 acc[4][4] = {};

  for (int kt = 0; kt < HID / 64; ++kt) {
    const int ko = kt * 64;
    gld16(Ag0 + ko, Al0);
    gld16(Ag1 + ko, Al1);
    gld16(Ag0 + ko + 32, Al2);
    gld16(Ag1 + ko + 32, Al3);
    gld16(Wg0 + ko, Bl0);
    gld16(Wg1 + ko, Bl1);
    gld16(Wg0 + ko + 32, Bl2);
    gld16(Wg1 + ko + 32, Bl3);
    __syncthreads();  // drains vmcnt -> both sub-tiles visible
#pragma unroll
    for (int s = 0; s < 2; ++s) {
      bf16x8 af[4], bfr[4];
#pragma unroll
      for (int i = 0; i < 4; ++i)
        af[i] = *(const bf16x8*)&As[s][(wr * 64 + i * 16 + lr) * 32 + lg * 8];
#pragma unroll
      for (int i = 0; i < 4; ++i)
        bfr[i] = *(const bf16x8*)&Bs[s][(wc * 64 + i * 16 + lr) * 32 + lg * 8];
#pragma unroll
      for (int mi = 0; mi < 4; ++mi)
#pragma unroll
        for (int ni = 0; ni < 4; ++ni)
          acc[mi][ni] = __builtin_amdgcn_mfma_f32_16x16x32_bf16(af[mi], bfr[ni], acc[mi][ni], 0, 0, 0);
    }
    __syncthreads();  // reads done -> next stage may overwrite
  }

  if (MODE == 0) {
#pragma unroll
    for (int mi = 0; mi < 4; ++mi) {
      int row = m0 + wr * 64 + mi * 16 + lg * 4;
#pragma unroll
      for (int ni = 0; ni < 4; ++ni) {
        int col = n0 + wc * 64 + ni * 16 + lr;
#pragma unroll
        for (int j = 0; j < 4; ++j)
          Cout[(size_t)(row + j) * HID + col] = acc[mi][ni][j];
      }
    }
  } else {
    unsigned short* obuf;
    const float* bptr;
    int cbase;
    bool transp = false;
    if (n0 < 4096) { obuf = Qb; bptr = bq; cbase = n0; }
    else if (n0 < 5120) { obuf = Kb; bptr = bk; cbase = n0 - 4096; }
    else { obuf = VTb; bptr = bv; cbase = n0 - 5120; transp = true; }
#pragma unroll
    for (int ni = 0; ni < 4; ++ni) {
      int c = cbase + wc * 64 + ni * 16 + lr;
      float bb = bptr[c];
      if (!transp) {
        int head = c >> 7, d = c & 127;
#pragma unroll
        for (int mi = 0; mi < 4; ++mi) {
          int row = m0 + wr * 64 + mi * 16 + lg * 4;
#pragma unroll
          for (int j = 0; j < 4; ++j)
            obuf[((size_t)head * S_LEN + row + j) * HD + d] = f2bf(acc[mi][ni][j] + bb);
        }
      } else {
#pragma unroll
        for (int mi = 0; mi < 4; ++mi) {
          int row = m0 + wr * 64 + mi * 16 + lg * 4;
          u16x4 pk;
#pragma unroll
          for (int j = 0; j < 4; ++j) pk[j] = f2bf(acc[mi][ni][j] + bb);
          *(u16x4*)&obuf[(size_t)c * S_LEN + row] = pk;
        }
      }
    }
  }
}

// ---------------- Flash attention ----------------
// grid (8, 32): 256 blocks, 8 waves, QBLK=128 (16 rows/wave), KVBLK=64.
// Block p handles q-tiles p and 15-p (34 KV tiles each -> balanced).
// Q pre-scaled (in rope_apply); defer-max (T13); reg prefetch (T14).
__global__ __launch_bounds__(512) void attn_fwd(const unsigned short* __restrict__ Qb,
                                                const unsigned short* __restrict__ Kb,
                                                const unsigned short* __restrict__ VTb,
                                                unsigned short* __restrict__ Ob) {
  __shared__ unsigned short Kl[64][136];
  __shared__ unsigned short Vt[128][72];
  __shared__ unsigned short Pl[8][16][72];
  int lin = blockIdx.x + 8 * blockIdx.y;
  int swz = (lin & 7) * 32 + (lin >> 3);  // each XCD owns 4 q-heads = 1 kv-head
  const int pair = swz & 7;
  const int h = swz >> 3;
  const int kh = h >> 2;
  const int tid = threadIdx.x, lane = tid & 63, wv = tid >> 6;
  const int lr = lane & 15, lg = lane >> 4;
  const int krow = tid >> 4, koff = (tid & 15) * 8;   // K rows krow, krow+32
  const int vrow = tid >> 3, voff = (tid & 7) * 8;    // V rows vrow, vrow+64
  const unsigned short* Kbase = Kb + (size_t)kh * S_LEN * HD;
  const unsigned short* Vbase = VTb + (size_t)kh * HD * S_LEN;

  for (int half = 0; half < 2; ++half) {
    const int qt = half ? 15 - pair : pair;
    const int q0 = qt * 128;
    const int nt = 2 * qt + 2;
    bf16x8 qf[4];
    {
      const unsigned short* qp = Qb + ((size_t)h * S_LEN + q0 + wv * 16 + lr) * HD + lg * 8;
#pragma unroll
      for (int s = 0; s < 4; ++s) qf[s] = *(const bf16x8*)(qp + s * 32);
    }
    f32x4 o[8];
#pragma unroll
    for (int i = 0; i < 8; ++i) o[i] = f32x4{0.f, 0.f, 0.f, 0.f};
    float mrow[4] = {-1e30f, -1e30f, -1e30f, -1e30f};
    float lrow[4] = {0.f, 0.f, 0.f, 0.f};

    u16x8 kreg[2], vreg[2];
    {
      const unsigned short* kp = Kbase + (size_t)krow * HD + koff;
      const unsigned short* vp = Vbase + (size_t)vrow * S_LEN + voff;
      kreg[0] = *(const u16x8*)kp;
      kreg[1] = *(const u16x8*)(kp + (size_t)32 * HD);
      vreg[0] = *(const u16x8*)vp;
      vreg[1] = *(const u16x8*)(vp + (size_t)64 * S_LEN);
    }
    __syncthreads();  // prior half's LDS readers done
    *(u16x8*)&Kl[krow][koff] = kreg[0];
    *(u16x8*)&Kl[krow + 32][koff] = kreg[1];
    *(u16x8*)&Vt[vrow][voff] = vreg[0];
    *(u16x8*)&Vt[vrow + 64][voff] = vreg[1];
    __syncthreads();

    for (int t = 0; t < nt; ++t) {
      if (t + 1 < nt) {  // T14: prefetch next tile into regs
        const unsigned short* kp = Kbase + ((size_t)(t + 1) * 64 + krow) * HD + koff;
        const unsigned short* vp = Vbase + (size_t)vrow * S_LEN + (t + 1) * 64 + voff;
        kreg[0] = *(const u16x8*)kp;
        kreg[1] = *(const u16x8*)(kp + (size_t)32 * HD);
        vreg[0] = *(const u16x8*)vp;
        vreg[1] = *(const u16x8*)(vp + (size_t)64 * S_LEN);
      }
      const int c0 = t * 64;
      const bool active = (c0 <= q0 + wv * 16 + 15);  // wave-uniform: skip fully-masked
      if (active) {
        f32x4 sf[4];
        __builtin_amdgcn_s_setprio(1);
#pragma unroll
        for (int c = 0; c < 4; ++c) {
          f32x4 s = {0.f, 0.f, 0.f, 0.f};
#pragma unroll
          for (int ss = 0; ss < 4; ++ss) {
            bf16x8 kf = *(const bf16x8*)&Kl[c * 16 + lr][ss * 32 + lg * 8];
            s = __builtin_amdgcn_mfma_f32_16x16x32_bf16(qf[ss], kf, s, 0, 0, 0);
          }
          sf[c] = s;
        }
        __builtin_amdgcn_s_setprio(0);

        if (t >= 2 * qt) {  // diagonal tiles only
#pragma unroll
          for (int c = 0; c < 4; ++c)
#pragma unroll
            for (int j = 0; j < 4; ++j)
              if ((c0 + c * 16 + lr) > (q0 + wv * 16 + lg * 4 + j)) sf[c][j] = -1e30f;
        }
        float tmax[4] = {-1e30f, -1e30f, -1e30f, -1e30f};
#pragma unroll
        for (int c = 0; c < 4; ++c)
#pragma unroll
          for (int j = 0; j < 4; ++j) tmax[j] = fmaxf(tmax[j], sf[c][j]);
#pragma unroll
        for (int dlt = 1; dlt < 16; dlt <<= 1)
#pragma unroll
          for (int j = 0; j < 4; ++j)
            tmax[j] = fmaxf(tmax[j], __shfl_xor(tmax[j], dlt, 64));

        // T13 defer-max: only rescale when max grows materially
        bool need = (tmax[0] > mrow[0] + 8.f) || (tmax[1] > mrow[1] + 8.f) ||
                    (tmax[2] > mrow[2] + 8.f) || (tmax[3] > mrow[3] + 8.f);
        if (__any(need)) {
          float alpha[4];
#pragma unroll
          for (int j = 0; j < 4; ++j) {
            float mn = fmaxf(mrow[j], tmax[j]);
            alpha[j] = exp2f(mrow[j] - mn);
            mrow[j] = mn;
          }
#pragma unroll
          for (int f = 0; f < 8; ++f)
#pragma unroll
            for (int j = 0; j < 4; ++j) o[f][j] *= alpha[j];
#pragma unroll
          for (int j = 0; j < 4; ++j) lrow[j] *= alpha[j];
        }
        float tsum[4] = {0.f, 0.f, 0.f, 0.f};
#pragma unroll
        for (int c = 0; c < 4; ++c)
#pragma unroll
          for (int j = 0; j < 4; ++j) {
            float pv = exp2f(sf[c][j] - mrow[j]);
            tsum[j] += pv;
            Pl[wv][lg * 4 + j][(c * 16 + lr) ^ ((lg & 2) << 2)] = f2bf(pv);
          }
#pragma unroll
        for (int dlt = 1; dlt < 16; dlt <<= 1)
#pragma unroll
          for (int j = 0; j < 4; ++j) tsum[j] += __shfl_xor(tsum[j], dlt, 64);
#pragma unroll
        for (int j = 0; j < 4; ++j) lrow[j] += tsum[j];

        // PV
        __builtin_amdgcn_s_setprio(1);
#pragma unroll
        for (int ks = 0; ks < 2; ++ks) {
          bf16x8 pa = *(const bf16x8*)&Pl[wv][lr][(ks * 32 + lg * 8) ^ (lr & 8)];
#pragma unroll
          for (int df = 0; df < 8; ++df) {
            bf16x8 vb = *(const bf16x8*)&Vt[df * 16 + lr][ks * 32 + lg * 8];
            o[df] = __builtin_amdgcn_mfma_f32_16x16x32_bf16(pa, vb, o[df], 0, 0, 0);
          }
        }
        __builtin_amdgcn_s_setprio(0);
      }

      if (t + 1 < nt) {
        __syncthreads();  // all waves done reading current tile
        *(u16x8*)&Kl[krow][koff] = kreg[0];
        *(u16x8*)&Kl[krow + 32][koff] = kreg[1];
        *(u16x8*)&Vt[vrow][voff] = vreg[0];
        *(u16x8*)&Vt[vrow + 64][voff] = vreg[1];
        __syncthreads();
      }
    }

#pragma unroll
    for (int j = 0; j < 4; ++j) {
      float inv = 1.0f / lrow[j];
      int row = q0 + wv * 16 + lg * 4 + j;
#pragma unroll
      for (int df = 0; df < 8; ++df)
        Ob[(size_t)row * (NH * HD) + h * HD + df * 16 + lr] = f2bf(o[df][j] * inv);
    }
  }
}

// ---------------- launch ----------------
extern "C" void kernel_launch(void* const* d_in, const int* in_sizes, int n_in,
                              void* d_out, int out_size, void* d_ws, size_t ws_size,
                              hipStream_t stream) {
  const float* hidden = (const float*)d_in[0];
  const float* wq = (const float*)d_in[1];
  const float* bq = (const float*)d_in[2];
  const float* wk = (const float*)d_in[3];
  const float* bk = (const float*)d_in[4];
  const float* wv = (const float*)d_in[5];
  const float* bv = (const float*)d_in[6];
  const float* wo = (const float*)d_in[7];
  float* out = (float*)d_out;

  char* p = (char*)d_ws;
  float* cs = (float*)p;                      p += (size_t)1 << 20;
  unsigned short* hb = (unsigned short*)p;    p += (size_t)16 << 20;
  unsigned short* Qb = (unsigned short*)p;    p += (size_t)16 << 20;
  unsigned short* Kbuf = (unsigned short*)p;  p += (size_t)4 << 20;
  unsigned short* VTb = (unsigned short*)p;   p += (size_t)4 << 20;
  unsigned short* attno = (unsigned short*)p; p += (size_t)16 << 20;
  unsigned short* wbuf = (unsigned short*)p;  // 48 MB reused (qkv weights, then wo)

  const float QSC = 0.08838834764831845f * 1.44269504088896340f;  // 1/sqrt(128)*log2e

  hipLaunchKernelGGL(rope_table, dim3(512), dim3(256), 0, stream, cs);
  hipLaunchKernelGGL(f2bf_kernel, dim3(4096), dim3(256), 0, stream, hidden, hb, S_LEN * HID / 8);
  hipLaunchKernelGGL(f2bf_kernel, dim3(8192), dim3(256), 0, stream, wq, wbuf, 4096 * HID / 8);
  hipLaunchKernelGGL(f2bf_kernel, dim3(2048), dim3(256), 0, stream, wk, wbuf + (size_t)4096 * HID, 1024 * HID / 8);
  hipLaunchKernelGGL(f2bf_kernel, dim3(2048), dim3(256), 0, stream, wv, wbuf + (size_t)5120 * HID, 1024 * HID / 8);
  hipLaunchKernelGGL((gemm_nt<1>), dim3(16, 48), dim3(256), 0, stream,
                     hb, wbuf, bq, bk, bv, Qb, Kbuf, VTb, (float*)nullptr);
  hipLaunchKernelGGL(rope_apply, dim3(16384), dim3(256), 0, stream, Qb, cs, QSC, NH * S_LEN * 64);
  hipLaunchKernelGGL(rope_apply, dim3(4096), dim3(256), 0, stream, Kbuf, cs, 1.0f, NKV * S_LEN * 64);
  hipLaunchKernelGGL(attn_fwd, dim3(8, 32), dim3(512), 0, stream, Qb, Kbuf, VTb, attno);
  hipLaunchKernelGGL(f2bf_kernel, dim3(8192), dim3(256), 0, stream, wo, wbuf, 4096 * HID / 8);
  hipLaunchKernelGGL((gemm_nt<0>), dim3(16, 32), dim3(256), 0, stream,
                     attno, wbuf, (const float*)nullptr, (const float*)nullptr, (const float*)nullptr,
                     (unsigned short*)nullptr, (unsigned short*)nullptr, (unsigned short*)nullptr, out);
}

// Round 8
// 369.824 us; speedup vs baseline: 1.0400x; 1.0313x over previous
//
#include <hip/hip_runtime.h>
#include <hip/hip_bf16.h>

#define S_LEN 2048
#define HID 4096
#define NH 32
#define NKV 8
#define HD 128

typedef __attribute__((ext_vector_type(4))) float f32x4;
typedef __attribute__((ext_vector_type(8))) __bf16 bf16x8;
typedef __attribute__((ext_vector_type(8))) unsigned short u16x8;
typedef __attribute__((ext_vector_type(4))) unsigned short u16x4;

static __device__ __forceinline__ unsigned short f2bf(float x) {
  return __builtin_bit_cast(unsigned short, __float2bfloat16(x));
}
static __device__ __forceinline__ float bf2f(unsigned short u) {
  return __builtin_bit_cast(float, (unsigned int)u << 16);
}
static __device__ __forceinline__ void gld16(const unsigned short* g, unsigned short* l) {
  __builtin_amdgcn_global_load_lds(
      (const __attribute__((address_space(1))) unsigned int*)g,
      (__attribute__((address_space(3))) unsigned int*)l, 16, 0, 0);
}

// ---------------- fp32 -> bf16 bulk convert ----------------
__global__ void f2bf_kernel(const float* __restrict__ in, unsigned short* __restrict__ out, int n8) {
  int i = blockIdx.x * 256 + threadIdx.x;
  if (i >= n8) return;
  f32x4 a = ((const f32x4*)in)[(size_t)i * 2];
  f32x4 b = ((const f32x4*)in)[(size_t)i * 2 + 1];
  u16x8 w;
#pragma unroll
  for (int j = 0; j < 4; ++j) {
    w[j] = f2bf(a[j]);
    w[4 + j] = f2bf(b[j]);
  }
  ((u16x8*)out)[(size_t)i] = w;
}

// ---------------- RoPE table ----------------
__global__ void rope_table(float* cs) {
  int idx = blockIdx.x * blockDim.x + threadIdx.x;
  if (idx >= S_LEN * 64) return;
  int d = idx & 63;
  int p = idx >> 6;
  float invf = exp2f(-(float)d * (19.9315685693241741f / 64.0f));  // theta^-d/64
  float ang = (float)p * invf;
  cs[idx] = cosf(ang);
  cs[S_LEN * 64 + idx] = sinf(ang);
}

// ---------------- RoPE apply (in-place, bf16 [head][S][128], x scale) ----------------
__global__ void rope_apply(unsigned short* __restrict__ buf, const float* __restrict__ cs,
                           float scale, int total) {
  int idx = blockIdx.x * blockDim.x + threadIdx.x;
  if (idx >= total) return;  // total = nheads * S * 64
  int d = idx & 63;
  int hp = idx >> 6;
  int pos = hp & (S_LEN - 1);
  size_t base = (size_t)hp * HD;
  float c = cs[pos * 64 + d];
  float s = cs[S_LEN * 64 + pos * 64 + d];
  float x1 = bf2f(buf[base + d]);
  float x2 = bf2f(buf[base + 64 + d]);
  buf[base + d] = f2bf((x1 * c - x2 * s) * scale);
  buf[base + 64 + d] = f2bf((x2 * c + x1 * s) * scale);
}

// ---------------- QKV GEMM (EXACT round-2 m97 structure, 852 TF measured) ----------------
// 128x128 tile, BK=32, single LDS buffer, global_load_lds(16B), 2 barriers/K-step.
// All structural variants (dbuf R3, frag-remap R4, split-K R6, BK=64 R7) REGRESSED.
// MODE 1 only: fused QKV epilogue -> Qb/Kb (bf16 [head][S][128], +bias), VTb ([n][S], +bias)
template <int MODE>
__global__ __launch_bounds__(256) void gemm_nt(
    const unsigned short* __restrict__ A, const unsigned short* __restrict__ W,
    const float* __restrict__ bq, const float* __restrict__ bk, const float* __restrict__ bv,
    unsigned short* __restrict__ Qb, unsigned short* __restrict__ Kb,
    unsigned short* __restrict__ VTb, float* __restrict__ Cout) {
  __shared__ unsigned short As[4096];  // [128 rows][32] linear
  __shared__ unsigned short Bs[4096];
  int lin = blockIdx.x + 16 * blockIdx.y;
  int cpx = (16 * gridDim.y) >> 3;
  int swz = (lin & 7) * cpx + (lin >> 3);
  const int m0 = (swz & 15) * 128;
  const int n0 = (swz >> 4) * 128;
  const int tid = threadIdx.x, lane = tid & 63, wv = tid >> 6;
  const int wr = wv >> 1, wc = wv & 1;
  const int lr = lane & 15, lg = lane >> 4;
  const int srow = lane >> 2, skk = (lane & 3) * 8;

  const unsigned short* Ag0 = A + (size_t)(m0 + wv * 32 + srow) * HID + skk;
  const unsigned short* Ag1 = Ag0 + (size_t)16 * HID;
  const unsigned short* Wg0 = W + (size_t)(n0 + wv * 32 + srow) * HID + skk;
  const unsigned short* Wg1 = Wg0 + (size_t)16 * HID;
  unsigned short* Al0 = As + wv * 1024;  // wave-uniform LDS slice bases
  unsigned short* Al1 = As + wv * 1024 + 512;
  unsigned short* Bl0 = Bs + wv * 1024;
  unsigned short* Bl1 = Bs + wv * 1024 + 512;

  f32x4 acc[4][4] = {};

  for (int kt = 0; kt < HID / 32; ++kt) {
    const int ko = kt * 32;
    gld16(Ag0 + ko, Al0);
    gld16(Ag1 + ko, Al1);
    gld16(Wg0 + ko, Bl0);
    gld16(Wg1 + ko, Bl1);
    __syncthreads();  // drains vmcnt -> tile visible
    bf16x8 af[4], bfr[4];
#pragma unroll
    for (int i = 0; i < 4; ++i)
      af[i] = *(const bf16x8*)&As[(wr * 64 + i * 16 + lr) * 32 + lg * 8];
#pragma unroll
    for (int i = 0; i < 4; ++i)
      bfr[i] = *(const bf16x8*)&Bs[(wc * 64 + i * 16 + lr) * 32 + lg * 8];
#pragma unroll
    for (int mi = 0; mi < 4; ++mi)
#pragma unroll
      for (int ni = 0; ni < 4; ++ni)
        acc[mi][ni] = __builtin_amdgcn_mfma_f32_16x16x32_bf16(af[mi], bfr[ni], acc[mi][ni], 0, 0, 0);
    __syncthreads();  // reads done -> next stage may overwrite
  }

  {
    unsigned short* obuf;
    const float* bptr;
    int cbase;
    bool transp = false;
    if (n0 < 4096) { obuf = Qb; bptr = bq; cbase = n0; }
    else if (n0 < 5120) { obuf = Kb; bptr = bk; cbase = n0 - 4096; }
    else { obuf = VTb; bptr = bv; cbase = n0 - 5120; transp = true; }
#pragma unroll
    for (int ni = 0; ni < 4; ++ni) {
      int c = cbase + wc * 64 + ni * 16 + lr;
      float bb = bptr[c];
      if (!transp) {
        int head = c >> 7, d = c & 127;
#pragma unroll
        for (int mi = 0; mi < 4; ++mi) {
          int row = m0 + wr * 64 + mi * 16 + lg * 4;
#pragma unroll
          for (int j = 0; j < 4; ++j)
            obuf[((size_t)head * S_LEN + row + j) * HD + d] = f2bf(acc[mi][ni][j] + bb);
        }
      } else {
#pragma unroll
        for (int mi = 0; mi < 4; ++mi) {
          int row = m0 + wr * 64 + mi * 16 + lg * 4;
          u16x4 pk;
#pragma unroll
          for (int j = 0; j < 4; ++j) pk[j] = f2bf(acc[mi][ni][j] + bb);
          *(u16x4*)&obuf[(size_t)c * S_LEN + row] = pk;
        }
      }
    }
  }
}

// ---------------- Out-projection: counted-vmcnt deep pipeline (T3+T4) ----------------
// C[2048][4096] fp32 = A[2048][4096]bf16 @ W[4096][4096]bf16^T.
// BM=256 x BN=128 -> grid 8x32 = 256 blocks = exactly 1/CU. 8 waves (2Mx4N).
// BK=64 as two [rows][32] subtiles (proven conflict-free ds_read/gld16 addressing).
// Schedule per K-tile: STAGE(next,6 gld16) -> s_waitcnt vmcnt(6) -> s_barrier ->
// ds_read+32 MFMA -> s_barrier. vmcnt NEVER 0 in main loop (T4, m218): next tile's
// loads stay in flight across both barriers, landing under the MFMA phase.
__global__ __launch_bounds__(512) void gemm_op8(const unsigned short* __restrict__ A,
                                                const unsigned short* __restrict__ W,
                                                float* __restrict__ Cout) {
  __shared__ __align__(16) unsigned short Asl[2][2][256 * 32];  // [buf][ksub] 64 KB
  __shared__ __align__(16) unsigned short Bsl[2][2][128 * 32];  // [buf][ksub] 32 KB
  int lin = blockIdx.x + 8 * blockIdx.y;
  int swz = (lin & 7) * 32 + (lin >> 3);  // XCD-chunked: 4 n-cols x 8 m per XCD (B-panel 4MB = L2)
  const int m0 = (swz & 7) * 256;
  const int n0 = (swz >> 3) * 128;
  const int tid = threadIdx.x, lane = tid & 63, wv = tid >> 6;
  const int wr = wv >> 2, wc = wv & 3;  // 2M x 4N waves, per-wave 128x32
  const int lr = lane & 15, lg = lane >> 4;

  // staging addresses: thread t covers row t>>2, col-chunk (t&3)*8 of a [128][32] slab
  const unsigned short* Ag = A + (size_t)(m0 + (tid >> 2)) * HID + (tid & 3) * 8;
  const unsigned short* Wg = W + (size_t)(n0 + (tid >> 2)) * HID + (tid & 3) * 8;
  const int wslab = (tid >> 6) * 512;  // wave-uniform LDS base offset (shorts)

  f32x4 acc[8][2] = {};

  // one K-tile stage: 4 A-issues (2 subtiles x 2 row-halves) + 2 B-issues = 6 gld16
#define STAGE_OP(buf, kt)                                                        \
  {                                                                              \
    const int ko_ = (kt)*64;                                                     \
    gld16(Ag + ko_, &Asl[buf][0][wslab]);                                        \
    gld16(Ag + ko_ + (size_t)128 * HID, &Asl[buf][0][4096 + wslab]);             \
    gld16(Ag + ko_ + 32, &Asl[buf][1][wslab]);                                   \
    gld16(Ag + ko_ + 32 + (size_t)128 * HID, &Asl[buf][1][4096 + wslab]);        \
    gld16(Wg + ko_, &Bsl[buf][0][wslab]);                                        \
    gld16(Wg + ko_ + 32, &Bsl[buf][1][wslab]);                                   \
  }

  STAGE_OP(0, 0);

  const int NT = HID / 64;  // 64
#pragma unroll 1
  for (int kt = 0; kt < NT; ++kt) {
    const int cur = kt & 1;
    if (kt + 1 < NT) {
      STAGE_OP(cur ^ 1, kt + 1);
      asm volatile("s_waitcnt vmcnt(6)" ::: "memory");  // wait current tile only
    } else {
      asm volatile("s_waitcnt vmcnt(0)" ::: "memory");  // epilogue drain
    }
    __builtin_amdgcn_s_barrier();  // all waves: current buffer fully staged
#pragma unroll
    for (int ks = 0; ks < 2; ++ks) {
      bf16x8 af[8], bfr[2];
#pragma unroll
      for (int i = 0; i < 8; ++i)
        af[i] = *(const bf16x8*)&Asl[cur][ks][(wr * 128 + i * 16 + lr) * 32 + lg * 8];
#pragma unroll
      for (int i = 0; i < 2; ++i)
        bfr[i] = *(const bf16x8*)&Bsl[cur][ks][(wc * 32 + i * 16 + lr) * 32 + lg * 8];
#pragma unroll
      for (int mi = 0; mi < 8; ++mi)
#pragma unroll
        for (int ni = 0; ni < 2; ++ni)
          acc[mi][ni] = __builtin_amdgcn_mfma_f32_16x16x32_bf16(af[mi], bfr[ni], acc[mi][ni], 0, 0, 0);
    }
    __builtin_amdgcn_s_barrier();  // all waves done reading -> next iter may overwrite
  }
#undef STAGE_OP

#pragma unroll
  for (int mi = 0; mi < 8; ++mi) {
    int row = m0 + wr * 128 + mi * 16 + lg * 4;
#pragma unroll
    for (int ni = 0; ni < 2; ++ni) {
      int col = n0 + wc * 32 + ni * 16 + lr;
#pragma unroll
      for (int j = 0; j < 4; ++j)
        Cout[(size_t)(row + j) * HID + col] = acc[mi][ni][j];
    }
  }
}

// ---------------- Flash attention (unchanged from round 5) ----------------
__global__ __launch_bounds__(512) void attn_fwd(const unsigned short* __restrict__ Qb,
                                                const unsigned short* __restrict__ Kb,
                                                const unsigned short* __restrict__ VTb,
                                                unsigned short* __restrict__ Ob) {
  __shared__ unsigned short Kl[64][136];
  __shared__ unsigned short Vt[128][72];
  __shared__ unsigned short Pl[8][16][72];
  int lin = blockIdx.x + 8 * blockIdx.y;
  int swz = (lin & 7) * 32 + (lin >> 3);  // each XCD owns 4 q-heads = 1 kv-head
  const int pair = swz & 7;
  const int h = swz >> 3;
  const int kh = h >> 2;
  const int tid = threadIdx.x, lane = tid & 63, wv = tid >> 6;
  const int lr = lane & 15, lg = lane >> 4;
  const int krow = tid >> 4, koff = (tid & 15) * 8;   // K rows krow, krow+32
  const int vrow = tid >> 3, voff = (tid & 7) * 8;    // V rows vrow, vrow+64
  const unsigned short* Kbase = Kb + (size_t)kh * S_LEN * HD;
  const unsigned short* Vbase = VTb + (size_t)kh * HD * S_LEN;

  for (int half = 0; half < 2; ++half) {
    const int qt = half ? 15 - pair : pair;
    const int q0 = qt * 128;
    const int nt = 2 * qt + 2;
    bf16x8 qf[4];
    {
      const unsigned short* qp = Qb + ((size_t)h * S_LEN + q0 + wv * 16 + lr) * HD + lg * 8;
#pragma unroll
      for (int s = 0; s < 4; ++s) qf[s] = *(const bf16x8*)(qp + s * 32);
    }
    f32x4 o[8];
#pragma unroll
    for (int i = 0; i < 8; ++i) o[i] = f32x4{0.f, 0.f, 0.f, 0.f};
    float mrow[4] = {-1e30f, -1e30f, -1e30f, -1e30f};
    float lrow[4] = {0.f, 0.f, 0.f, 0.f};

    u16x8 kreg[2], vreg[2];
    {
      const unsigned short* kp = Kbase + (size_t)krow * HD + koff;
      const unsigned short* vp = Vbase + (size_t)vrow * S_LEN + voff;
      kreg[0] = *(const u16x8*)kp;
      kreg[1] = *(const u16x8*)(kp + (size_t)32 * HD);
      vreg[0] = *(const u16x8*)vp;
      vreg[1] = *(const u16x8*)(vp + (size_t)64 * S_LEN);
    }
    __syncthreads();  // prior half's LDS readers done
    *(u16x8*)&Kl[krow][koff] = kreg[0];
    *(u16x8*)&Kl[krow + 32][koff] = kreg[1];
    *(u16x8*)&Vt[vrow][voff] = vreg[0];
    *(u16x8*)&Vt[vrow + 64][voff] = vreg[1];
    __syncthreads();

    for (int t = 0; t < nt; ++t) {
      if (t + 1 < nt) {  // T14: prefetch next tile into regs
        const unsigned short* kp = Kbase + ((size_t)(t + 1) * 64 + krow) * HD + koff;
        const unsigned short* vp = Vbase + (size_t)vrow * S_LEN + (t + 1) * 64 + voff;
        kreg[0] = *(const u16x8*)kp;
        kreg[1] = *(const u16x8*)(kp + (size_t)32 * HD);
        vreg[0] = *(const u16x8*)vp;
        vreg[1] = *(const u16x8*)(vp + (size_t)64 * S_LEN);
      }
      const int c0 = t * 64;
      const bool active = (c0 <= q0 + wv * 16 + 15);  // wave-uniform: skip fully-masked
      if (active) {
        f32x4 sf[4];
        __builtin_amdgcn_s_setprio(1);
#pragma unroll
        for (int c = 0; c < 4; ++c) {
          f32x4 s = {0.f, 0.f, 0.f, 0.f};
#pragma unroll
          for (int ss = 0; ss < 4; ++ss) {
            bf16x8 kf = *(const bf16x8*)&Kl[c * 16 + lr][ss * 32 + lg * 8];
            s = __builtin_amdgcn_mfma_f32_16x16x32_bf16(qf[ss], kf, s, 0, 0, 0);
          }
          sf[c] = s;
        }
        __builtin_amdgcn_s_setprio(0);

        if (t >= 2 * qt) {  // diagonal tiles only
#pragma unroll
          for (int c = 0; c < 4; ++c)
#pragma unroll
            for (int j = 0; j < 4; ++j)
              if ((c0 + c * 16 + lr) > (q0 + wv * 16 + lg * 4 + j)) sf[c][j] = -1e30f;
        }
        float tmax[4] = {-1e30f, -1e30f, -1e30f, -1e30f};
#pragma unroll
        for (int c = 0; c < 4; ++c)
#pragma unroll
          for (int j = 0; j < 4; ++j) tmax[j] = fmaxf(tmax[j], sf[c][j]);
#pragma unroll
        for (int dlt = 1; dlt < 16; dlt <<= 1)
#pragma unroll
          for (int j = 0; j < 4; ++j)
            tmax[j] = fmaxf(tmax[j], __shfl_xor(tmax[j], dlt, 64));

        // T13 defer-max: only rescale when max grows materially
        bool need = (tmax[0] > mrow[0] + 8.f) || (tmax[1] > mrow[1] + 8.f) ||
                    (tmax[2] > mrow[2] + 8.f) || (tmax[3] > mrow[3] + 8.f);
        if (__any(need)) {
          float alpha[4];
#pragma unroll
          for (int j = 0; j < 4; ++j) {
            float mn = fmaxf(mrow[j], tmax[j]);
            alpha[j] = exp2f(mrow[j] - mn);
            mrow[j] = mn;
          }
#pragma unroll
          for (int f = 0; f < 8; ++f)
#pragma unroll
            for (int j = 0; j < 4; ++j) o[f][j] *= alpha[j];
#pragma unroll
          for (int j = 0; j < 4; ++j) lrow[j] *= alpha[j];
        }
        float tsum[4] = {0.f, 0.f, 0.f, 0.f};
#pragma unroll
        for (int c = 0; c < 4; ++c)
#pragma unroll
          for (int j = 0; j < 4; ++j) {
            float pv = exp2f(sf[c][j] - mrow[j]);
            tsum[j] += pv;
            Pl[wv][lg * 4 + j][(c * 16 + lr) ^ ((lg & 2) << 2)] = f2bf(pv);
          }
#pragma unroll
        for (int dlt = 1; dlt < 16; dlt <<= 1)
#pragma unroll
          for (int j = 0; j < 4; ++j) tsum[j] += __shfl_xor(tsum[j], dlt, 64);
#pragma unroll
        for (int j = 0; j < 4; ++j) lrow[j] += tsum[j];

        // PV
        __builtin_amdgcn_s_setprio(1);
#pragma unroll
        for (int ks = 0; ks < 2; ++ks) {
          bf16x8 pa = *(const bf16x8*)&Pl[wv][lr][(ks * 32 + lg * 8) ^ (lr & 8)];
#pragma unroll
          for (int df = 0; df < 8; ++df) {
            bf16x8 vb = *(const bf16x8*)&Vt[df * 16 + lr][ks * 32 + lg * 8];
            o[df] = __builtin_amdgcn_mfma_f32_16x16x32_bf16(pa, vb, o[df], 0, 0, 0);
          }
        }
        __builtin_amdgcn_s_setprio(0);
      }

      if (t + 1 < nt) {
        __syncthreads();  // all waves done reading current tile
        *(u16x8*)&Kl[krow][koff] = kreg[0];
        *(u16x8*)&Kl[krow + 32][koff] = kreg[1];
        *(u16x8*)&Vt[vrow][voff] = vreg[0];
        *(u16x8*)&Vt[vrow + 64][voff] = vreg[1];
        __syncthreads();
      }
    }

#pragma unroll
    for (int j = 0; j < 4; ++j) {
      float inv = 1.0f / lrow[j];
      int row = q0 + wv * 16 + lg * 4 + j;
#pragma unroll
      for (int df = 0; df < 8; ++df)
        Ob[(size_t)row * (NH * HD) + h * HD + df * 16 + lr] = f2bf(o[df][j] * inv);
    }
  }
}

// ---------------- launch ----------------
extern "C" void kernel_launch(void* const* d_in, const int* in_sizes, int n_in,
                              void* d_out, int out_size, void* d_ws, size_t ws_size,
                              hipStream_t stream) {
  const float* hidden = (const float*)d_in[0];
  const float* wq = (const float*)d_in[1];
  const float* bq = (const float*)d_in[2];
  const float* wk = (const float*)d_in[3];
  const float* bk = (const float*)d_in[4];
  const float* wv = (const float*)d_in[5];
  const float* bv = (const float*)d_in[6];
  const float* wo = (const float*)d_in[7];
  float* out = (float*)d_out;

  char* p = (char*)d_ws;
  float* cs = (float*)p;                      p += (size_t)1 << 20;
  unsigned short* hb = (unsigned short*)p;    p += (size_t)16 << 20;
  unsigned short* Qb = (unsigned short*)p;    p += (size_t)16 << 20;
  unsigned short* Kbuf = (unsigned short*)p;  p += (size_t)4 << 20;
  unsigned short* VTb = (unsigned short*)p;   p += (size_t)4 << 20;
  unsigned short* attno = (unsigned short*)p; p += (size_t)16 << 20;
  unsigned short* wbuf = (unsigned short*)p;  // 48 MB reused (qkv weights, then wo)

  const float QSC = 0.08838834764831845f * 1.44269504088896340f;  // 1/sqrt(128)*log2e

  hipLaunchKernelGGL(rope_table, dim3(512), dim3(256), 0, stream, cs);
  hipLaunchKernelGGL(f2bf_kernel, dim3(4096), dim3(256), 0, stream, hidden, hb, S_LEN * HID / 8);
  hipLaunchKernelGGL(f2bf_kernel, dim3(8192), dim3(256), 0, stream, wq, wbuf, 4096 * HID / 8);
  hipLaunchKernelGGL(f2bf_kernel, dim3(2048), dim3(256), 0, stream, wk, wbuf + (size_t)4096 * HID, 1024 * HID / 8);
  hipLaunchKernelGGL(f2bf_kernel, dim3(2048), dim3(256), 0, stream, wv, wbuf + (size_t)5120 * HID, 1024 * HID / 8);
  hipLaunchKernelGGL((gemm_nt<1>), dim3(16, 48), dim3(256), 0, stream,
                     hb, wbuf, bq, bk, bv, Qb, Kbuf, VTb, (float*)nullptr);
  hipLaunchKernelGGL(rope_apply, dim3(16384), dim3(256), 0, stream, Qb, cs, QSC, NH * S_LEN * 64);
  hipLaunchKernelGGL(rope_apply, dim3(4096), dim3(256), 0, stream, Kbuf, cs, 1.0f, NKV * S_LEN * 64);
  hipLaunchKernelGGL(attn_fwd, dim3(8, 32), dim3(512), 0, stream, Qb, Kbuf, VTb, attno);
  hipLaunchKernelGGL(f2bf_kernel, dim3(8192), dim3(256), 0, stream, wo, wbuf, 4096 * HID / 8);
  hipLaunchKernelGGL(gemm_op8, dim3(8, 32), dim3(512), 0, stream, attno, wbuf, out);
}

// Round 9
// 365.489 us; speedup vs baseline: 1.0523x; 1.0119x over previous
//
#include <hip/hip_runtime.h>
#include <hip/hip_bf16.h>

#define S_LEN 2048
#define HID 4096
#define NH 32
#define NKV 8
#define HD 128

typedef __attribute__((ext_vector_type(4))) float f32x4;
typedef __attribute__((ext_vector_type(8))) __bf16 bf16x8;
typedef __attribute__((ext_vector_type(8))) unsigned short u16x8;
typedef __attribute__((ext_vector_type(4))) unsigned short u16x4;

static __device__ __forceinline__ unsigned short f2bf(float x) {
  return __builtin_bit_cast(unsigned short, __float2bfloat16(x));
}
static __device__ __forceinline__ float bf2f(unsigned short u) {
  return __builtin_bit_cast(float, (unsigned int)u << 16);
}
static __device__ __forceinline__ void gld16(const unsigned short* g, unsigned short* l) {
  __builtin_amdgcn_global_load_lds(
      (const __attribute__((address_space(1))) unsigned int*)g,
      (__attribute__((address_space(3))) unsigned int*)l, 16, 0, 0);
}

// ---------------- fp32 -> bf16 bulk convert ----------------
__global__ void f2bf_kernel(const float* __restrict__ in, unsigned short* __restrict__ out, int n8) {
  int i = blockIdx.x * 256 + threadIdx.x;
  if (i >= n8) return;
  f32x4 a = ((const f32x4*)in)[(size_t)i * 2];
  f32x4 b = ((const f32x4*)in)[(size_t)i * 2 + 1];
  u16x8 w;
#pragma unroll
  for (int j = 0; j < 4; ++j) {
    w[j] = f2bf(a[j]);
    w[4 + j] = f2bf(b[j]);
  }
  ((u16x8*)out)[(size_t)i] = w;
}

// ---------------- RoPE table ----------------
__global__ void rope_table(float* cs) {
  int idx = blockIdx.x * blockDim.x + threadIdx.x;
  if (idx >= S_LEN * 64) return;
  int d = idx & 63;
  int p = idx >> 6;
  float invf = exp2f(-(float)d * (19.9315685693241741f / 64.0f));  // theta^-d/64
  float ang = (float)p * invf;
  cs[idx] = cosf(ang);
  cs[S_LEN * 64 + idx] = sinf(ang);
}

// ---------------- RoPE apply (in-place, bf16 [head][S][128], x scale) ----------------
__global__ void rope_apply(unsigned short* __restrict__ buf, const float* __restrict__ cs,
                           float scale, int total) {
  int idx = blockIdx.x * blockDim.x + threadIdx.x;
  if (idx >= total) return;  // total = nheads * S * 64
  int d = idx & 63;
  int hp = idx >> 6;
  int pos = hp & (S_LEN - 1);
  size_t base = (size_t)hp * HD;
  float c = cs[pos * 64 + d];
  float s = cs[S_LEN * 64 + pos * 64 + d];
  float x1 = bf2f(buf[base + d]);
  float x2 = bf2f(buf[base + 64 + d]);
  buf[base + d] = f2bf((x1 * c - x2 * s) * scale);
  buf[base + 64 + d] = f2bf((x2 * c + x1 * s) * scale);
}

// ---------------- QKV GEMM (EXACT round-2 m97 structure, 852 TF measured) ----------------
// 128x128 tile, BK=32, single LDS buffer, global_load_lds(16B), 2 barriers/K-step.
// All structural variants (dbuf R3, frag-remap R4, split-K R6, BK=64 R7) REGRESSED.
// MODE 1 only: fused QKV epilogue -> Qb/Kb (bf16 [head][S][128], +bias), VTb ([n][S], +bias)
template <int MODE>
__global__ __launch_bounds__(256) void gemm_nt(
    const unsigned short* __restrict__ A, const unsigned short* __restrict__ W,
    const float* __restrict__ bq, const float* __restrict__ bk, const float* __restrict__ bv,
    unsigned short* __restrict__ Qb, unsigned short* __restrict__ Kb,
    unsigned short* __restrict__ VTb, float* __restrict__ Cout) {
  __shared__ unsigned short As[4096];  // [128 rows][32] linear
  __shared__ unsigned short Bs[4096];
  int lin = blockIdx.x + 16 * blockIdx.y;
  int cpx = (16 * gridDim.y) >> 3;
  int swz = (lin & 7) * cpx + (lin >> 3);
  const int m0 = (swz & 15) * 128;
  const int n0 = (swz >> 4) * 128;
  const int tid = threadIdx.x, lane = tid & 63, wv = tid >> 6;
  const int wr = wv >> 1, wc = wv & 1;
  const int lr = lane & 15, lg = lane >> 4;
  const int srow = lane >> 2, skk = (lane & 3) * 8;

  const unsigned short* Ag0 = A + (size_t)(m0 + wv * 32 + srow) * HID + skk;
  const unsigned short* Ag1 = Ag0 + (size_t)16 * HID;
  const unsigned short* Wg0 = W + (size_t)(n0 + wv * 32 + srow) * HID + skk;
  const unsigned short* Wg1 = Wg0 + (size_t)16 * HID;
  unsigned short* Al0 = As + wv * 1024;  // wave-uniform LDS slice bases
  unsigned short* Al1 = As + wv * 1024 + 512;
  unsigned short* Bl0 = Bs + wv * 1024;
  unsigned short* Bl1 = Bs + wv * 1024 + 512;

  f32x4 acc[4][4] = {};

  for (int kt = 0; kt < HID / 32; ++kt) {
    const int ko = kt * 32;
    gld16(Ag0 + ko, Al0);
    gld16(Ag1 + ko, Al1);
    gld16(Wg0 + ko, Bl0);
    gld16(Wg1 + ko, Bl1);
    __syncthreads();  // drains vmcnt -> tile visible
    bf16x8 af[4], bfr[4];
#pragma unroll
    for (int i = 0; i < 4; ++i)
      af[i] = *(const bf16x8*)&As[(wr * 64 + i * 16 + lr) * 32 + lg * 8];
#pragma unroll
    for (int i = 0; i < 4; ++i)
      bfr[i] = *(const bf16x8*)&Bs[(wc * 64 + i * 16 + lr) * 32 + lg * 8];
#pragma unroll
    for (int mi = 0; mi < 4; ++mi)
#pragma unroll
      for (int ni = 0; ni < 4; ++ni)
        acc[mi][ni] = __builtin_amdgcn_mfma_f32_16x16x32_bf16(af[mi], bfr[ni], acc[mi][ni], 0, 0, 0);
    __syncthreads();  // reads done -> next stage may overwrite
  }

  {
    unsigned short* obuf;
    const float* bptr;
    int cbase;
    bool transp = false;
    if (n0 < 4096) { obuf = Qb; bptr = bq; cbase = n0; }
    else if (n0 < 5120) { obuf = Kb; bptr = bk; cbase = n0 - 4096; }
    else { obuf = VTb; bptr = bv; cbase = n0 - 5120; transp = true; }
#pragma unroll
    for (int ni = 0; ni < 4; ++ni) {
      int c = cbase + wc * 64 + ni * 16 + lr;
      float bb = bptr[c];
      if (!transp) {
        int head = c >> 7, d = c & 127;
#pragma unroll
        for (int mi = 0; mi < 4; ++mi) {
          int row = m0 + wr * 64 + mi * 16 + lg * 4;
#pragma unroll
          for (int j = 0; j < 4; ++j)
            obuf[((size_t)head * S_LEN + row + j) * HD + d] = f2bf(acc[mi][ni][j] + bb);
        }
      } else {
#pragma unroll
        for (int mi = 0; mi < 4; ++mi) {
          int row = m0 + wr * 64 + mi * 16 + lg * 4;
          u16x4 pk;
#pragma unroll
          for (int j = 0; j < 4; ++j) pk[j] = f2bf(acc[mi][ni][j] + bb);
          *(u16x4*)&obuf[(size_t)c * S_LEN + row] = pk;
        }
      }
    }
  }
}

// ---------------- Out-projection: depth-2 counted-vmcnt pipeline (T3+T4) ----------------
// C[2048][4096] fp32 = A[2048][4096]bf16 @ W[4096][4096]bf16^T.
// BM=256 x BN=128 -> grid 8x32 = 256 blocks = exactly 1/CU. 8 waves as 4M x 2N
// (per-wave 64x64, af4+bfr4 = same fragment pattern as proven QKV kernel).
// TRIPLE-buffered LDS (3 x 48KB = 144KB): STAGE(kt+2) -> vmcnt(12) -> barrier ->
// compute(kt) -> barrier. A tile's loads get TWO compute phases (~620cy) to land,
// covering HBM latency (R8's depth-1 version only gave one phase -> 50% stall).
__global__ __launch_bounds__(512) void gemm_op8(const unsigned short* __restrict__ A,
                                                const unsigned short* __restrict__ W,
                                                float* __restrict__ Cout) {
  __shared__ __align__(16) unsigned short Asl[3][2][256 * 32];  // 96 KB
  __shared__ __align__(16) unsigned short Bsl[3][2][128 * 32];  // 48 KB
  int lin = blockIdx.x + 8 * blockIdx.y;
  int swz = (lin & 7) * 32 + (lin >> 3);  // XCD-chunked: 4 n-cols x 8 m per XCD
  const int m0 = (swz & 7) * 256;
  const int n0 = (swz >> 3) * 128;
  const int tid = threadIdx.x, lane = tid & 63, wv = tid >> 6;
  const int wr = wv >> 1, wc = wv & 1;  // 4M x 2N waves, per-wave 64x64
  const int lr = lane & 15, lg = lane >> 4;

  // staging: thread t covers row t>>2, col-chunk (t&3)*8 of a [128][32] slab
  const unsigned short* Ag = A + (size_t)(m0 + (tid >> 2)) * HID + (tid & 3) * 8;
  const unsigned short* Wg = W + (size_t)(n0 + (tid >> 2)) * HID + (tid & 3) * 8;
  const int wslab = wv * 512;  // wave-uniform LDS base offset (shorts)

  f32x4 acc[4][4] = {};

  // one K64-tile stage: 4 A-issues (2 subtiles x 2 row-halves) + 2 B-issues = 6 gld16
#define STAGE_OP(buf, kt)                                                        \
  {                                                                              \
    const int ko_ = (kt)*64;                                                     \
    gld16(Ag + ko_, &Asl[buf][0][wslab]);                                        \
    gld16(Ag + ko_ + (size_t)128 * HID, &Asl[buf][0][4096 + wslab]);             \
    gld16(Ag + ko_ + 32, &Asl[buf][1][wslab]);                                   \
    gld16(Ag + ko_ + 32 + (size_t)128 * HID, &Asl[buf][1][4096 + wslab]);        \
    gld16(Wg + ko_, &Bsl[buf][0][wslab]);                                        \
    gld16(Wg + ko_ + 32, &Bsl[buf][1][wslab]);                                   \
  }

  STAGE_OP(0, 0);
  STAGE_OP(1, 1);

  const int NT = HID / 64;  // 64
#pragma unroll 1
  for (int kt = 0; kt < NT; ++kt) {
    const int cur = kt % 3;
    if (kt + 2 < NT) {
      STAGE_OP((kt + 2) % 3, kt + 2);
      asm volatile("s_waitcnt vmcnt(12)" ::: "memory");  // tile kt done; kt+1,kt+2 in flight
    } else if (kt + 1 < NT) {
      asm volatile("s_waitcnt vmcnt(6)" ::: "memory");   // tile kt done; kt+1 in flight
    } else {
      asm volatile("s_waitcnt vmcnt(0)" ::: "memory");   // final drain
    }
    __builtin_amdgcn_s_barrier();  // all waves: buffer cur fully staged
#pragma unroll
    for (int ks = 0; ks < 2; ++ks) {
      bf16x8 af[4], bfr[4];
#pragma unroll
      for (int i = 0; i < 4; ++i)
        af[i] = *(const bf16x8*)&Asl[cur][ks][(wr * 64 + i * 16 + lr) * 32 + lg * 8];
#pragma unroll
      for (int i = 0; i < 4; ++i)
        bfr[i] = *(const bf16x8*)&Bsl[cur][ks][(wc * 64 + i * 16 + lr) * 32 + lg * 8];
#pragma unroll
      for (int mi = 0; mi < 4; ++mi)
#pragma unroll
        for (int ni = 0; ni < 4; ++ni)
          acc[mi][ni] = __builtin_amdgcn_mfma_f32_16x16x32_bf16(af[mi], bfr[ni], acc[mi][ni], 0, 0, 0);
    }
    __builtin_amdgcn_s_barrier();  // all waves done reading -> buffer may be overwritten
  }
#undef STAGE_OP

#pragma unroll
  for (int mi = 0; mi < 4; ++mi) {
    int row = m0 + wr * 64 + mi * 16 + lg * 4;
#pragma unroll
    for (int ni = 0; ni < 4; ++ni) {
      int col = n0 + wc * 64 + ni * 16 + lr;
#pragma unroll
      for (int j = 0; j < 4; ++j)
        Cout[(size_t)(row + j) * HID + col] = acc[mi][ni][j];
    }
  }
}

// ---------------- Flash attention (unchanged from round 5) ----------------
__global__ __launch_bounds__(512) void attn_fwd(const unsigned short* __restrict__ Qb,
                                                const unsigned short* __restrict__ Kb,
                                                const unsigned short* __restrict__ VTb,
                                                unsigned short* __restrict__ Ob) {
  __shared__ unsigned short Kl[64][136];
  __shared__ unsigned short Vt[128][72];
  __shared__ unsigned short Pl[8][16][72];
  int lin = blockIdx.x + 8 * blockIdx.y;
  int swz = (lin & 7) * 32 + (lin >> 3);  // each XCD owns 4 q-heads = 1 kv-head
  const int pair = swz & 7;
  const int h = swz >> 3;
  const int kh = h >> 2;
  const int tid = threadIdx.x, lane = tid & 63, wv = tid >> 6;
  const int lr = lane & 15, lg = lane >> 4;
  const int krow = tid >> 4, koff = (tid & 15) * 8;   // K rows krow, krow+32
  const int vrow = tid >> 3, voff = (tid & 7) * 8;    // V rows vrow, vrow+64
  const unsigned short* Kbase = Kb + (size_t)kh * S_LEN * HD;
  const unsigned short* Vbase = VTb + (size_t)kh * HD * S_LEN;

  for (int half = 0; half < 2; ++half) {
    const int qt = half ? 15 - pair : pair;
    const int q0 = qt * 128;
    const int nt = 2 * qt + 2;
    bf16x8 qf[4];
    {
      const unsigned short* qp = Qb + ((size_t)h * S_LEN + q0 + wv * 16 + lr) * HD + lg * 8;
#pragma unroll
      for (int s = 0; s < 4; ++s) qf[s] = *(const bf16x8*)(qp + s * 32);
    }
    f32x4 o[8];
#pragma unroll
    for (int i = 0; i < 8; ++i) o[i] = f32x4{0.f, 0.f, 0.f, 0.f};
    float mrow[4] = {-1e30f, -1e30f, -1e30f, -1e30f};
    float lrow[4] = {0.f, 0.f, 0.f, 0.f};

    u16x8 kreg[2], vreg[2];
    {
      const unsigned short* kp = Kbase + (size_t)krow * HD + koff;
      const unsigned short* vp = Vbase + (size_t)vrow * S_LEN + voff;
      kreg[0] = *(const u16x8*)kp;
      kreg[1] = *(const u16x8*)(kp + (size_t)32 * HD);
      vreg[0] = *(const u16x8*)vp;
      vreg[1] = *(const u16x8*)(vp + (size_t)64 * S_LEN);
    }
    __syncthreads();  // prior half's LDS readers done
    *(u16x8*)&Kl[krow][koff] = kreg[0];
    *(u16x8*)&Kl[krow + 32][koff] = kreg[1];
    *(u16x8*)&Vt[vrow][voff] = vreg[0];
    *(u16x8*)&Vt[vrow + 64][voff] = vreg[1];
    __syncthreads();

    for (int t = 0; t < nt; ++t) {
      if (t + 1 < nt) {  // T14: prefetch next tile into regs
        const unsigned short* kp = Kbase + ((size_t)(t + 1) * 64 + krow) * HD + koff;
        const unsigned short* vp = Vbase + (size_t)vrow * S_LEN + (t + 1) * 64 + voff;
        kreg[0] = *(const u16x8*)kp;
        kreg[1] = *(const u16x8*)(kp + (size_t)32 * HD);
        vreg[0] = *(const u16x8*)vp;
        vreg[1] = *(const u16x8*)(vp + (size_t)64 * S_LEN);
      }
      const int c0 = t * 64;
      const bool active = (c0 <= q0 + wv * 16 + 15);  // wave-uniform: skip fully-masked
      if (active) {
        f32x4 sf[4];
        __builtin_amdgcn_s_setprio(1);
#pragma unroll
        for (int c = 0; c < 4; ++c) {
          f32x4 s = {0.f, 0.f, 0.f, 0.f};
#pragma unroll
          for (int ss = 0; ss < 4; ++ss) {
            bf16x8 kf = *(const bf16x8*)&Kl[c * 16 + lr][ss * 32 + lg * 8];
            s = __builtin_amdgcn_mfma_f32_16x16x32_bf16(qf[ss], kf, s, 0, 0, 0);
          }
          sf[c] = s;
        }
        __builtin_amdgcn_s_setprio(0);

        if (t >= 2 * qt) {  // diagonal tiles only
#pragma unroll
          for (int c = 0; c < 4; ++c)
#pragma unroll
            for (int j = 0; j < 4; ++j)
              if ((c0 + c * 16 + lr) > (q0 + wv * 16 + lg * 4 + j)) sf[c][j] = -1e30f;
        }
        float tmax[4] = {-1e30f, -1e30f, -1e30f, -1e30f};
#pragma unroll
        for (int c = 0; c < 4; ++c)
#pragma unroll
          for (int j = 0; j < 4; ++j) tmax[j] = fmaxf(tmax[j], sf[c][j]);
#pragma unroll
        for (int dlt = 1; dlt < 16; dlt <<= 1)
#pragma unroll
          for (int j = 0; j < 4; ++j)
            tmax[j] = fmaxf(tmax[j], __shfl_xor(tmax[j], dlt, 64));

        // T13 defer-max: only rescale when max grows materially
        bool need = (tmax[0] > mrow[0] + 8.f) || (tmax[1] > mrow[1] + 8.f) ||
                    (tmax[2] > mrow[2] + 8.f) || (tmax[3] > mrow[3] + 8.f);
        if (__any(need)) {
          float alpha[4];
#pragma unroll
          for (int j = 0; j < 4; ++j) {
            float mn = fmaxf(mrow[j], tmax[j]);
            alpha[j] = exp2f(mrow[j] - mn);
            mrow[j] = mn;
          }
#pragma unroll
          for (int f = 0; f < 8; ++f)
#pragma unroll
            for (int j = 0; j < 4; ++j) o[f][j] *= alpha[j];
#pragma unroll
          for (int j = 0; j < 4; ++j) lrow[j] *= alpha[j];
        }
        float tsum[4] = {0.f, 0.f, 0.f, 0.f};
#pragma unroll
        for (int c = 0; c < 4; ++c)
#pragma unroll
          for (int j = 0; j < 4; ++j) {
            float pv = exp2f(sf[c][j] - mrow[j]);
            tsum[j] += pv;
            Pl[wv][lg * 4 + j][(c * 16 + lr) ^ ((lg & 2) << 2)] = f2bf(pv);
          }
#pragma unroll
        for (int dlt = 1; dlt < 16; dlt <<= 1)
#pragma unroll
          for (int j = 0; j < 4; ++j) tsum[j] += __shfl_xor(tsum[j], dlt, 64);
#pragma unroll
        for (int j = 0; j < 4; ++j) lrow[j] += tsum[j];

        // PV
        __builtin_amdgcn_s_setprio(1);
#pragma unroll
        for (int ks = 0; ks < 2; ++ks) {
          bf16x8 pa = *(const bf16x8*)&Pl[wv][lr][(ks * 32 + lg * 8) ^ (lr & 8)];
#pragma unroll
          for (int df = 0; df < 8; ++df) {
            bf16x8 vb = *(const bf16x8*)&Vt[df * 16 + lr][ks * 32 + lg * 8];
            o[df] = __builtin_amdgcn_mfma_f32_16x16x32_bf16(pa, vb, o[df], 0, 0, 0);
          }
        }
        __builtin_amdgcn_s_setprio(0);
      }

      if (t + 1 < nt) {
        __syncthreads();  // all waves done reading current tile
        *(u16x8*)&Kl[krow][koff] = kreg[0];
        *(u16x8*)&Kl[krow + 32][koff] = kreg[1];
        *(u16x8*)&Vt[vrow][voff] = vreg[0];
        *(u16x8*)&Vt[vrow + 64][voff] = vreg[1];
        __syncthreads();
      }
    }

#pragma unroll
    for (int j = 0; j < 4; ++j) {
      float inv = 1.0f / lrow[j];
      int row = q0 + wv * 16 + lg * 4 + j;
#pragma unroll
      for (int df = 0; df < 8; ++df)
        Ob[(size_t)row * (NH * HD) + h * HD + df * 16 + lr] = f2bf(o[df][j] * inv);
    }
  }
}

// ---------------- launch ----------------
extern "C" void kernel_launch(void* const* d_in, const int* in_sizes, int n_in,
                              void* d_out, int out_size, void* d_ws, size_t ws_size,
                              hipStream_t stream) {
  const float* hidden = (const float*)d_in[0];
  const float* wq = (const float*)d_in[1];
  const float* bq = (const float*)d_in[2];
  const float* wk = (const float*)d_in[3];
  const float* bk = (const float*)d_in[4];
  const float* wv = (const float*)d_in[5];
  const float* bv = (const float*)d_in[6];
  const float* wo = (const float*)d_in[7];
  float* out = (float*)d_out;

  char* p = (char*)d_ws;
  float* cs = (float*)p;                      p += (size_t)1 << 20;
  unsigned short* hb = (unsigned short*)p;    p += (size_t)16 << 20;
  unsigned short* Qb = (unsigned short*)p;    p += (size_t)16 << 20;
  unsigned short* Kbuf = (unsigned short*)p;  p += (size_t)4 << 20;
  unsigned short* VTb = (unsigned short*)p;   p += (size_t)4 << 20;
  unsigned short* attno = (unsigned short*)p; p += (size_t)16 << 20;
  unsigned short* wbuf = (unsigned short*)p;  // 48 MB reused (qkv weights, then wo)

  const float QSC = 0.08838834764831845f * 1.44269504088896340f;  // 1/sqrt(128)*log2e

  hipLaunchKernelGGL(rope_table, dim3(512), dim3(256), 0, stream, cs);
  hipLaunchKernelGGL(f2bf_kernel, dim3(4096), dim3(256), 0, stream, hidden, hb, S_LEN * HID / 8);
  hipLaunchKernelGGL(f2bf_kernel, dim3(8192), dim3(256), 0, stream, wq, wbuf, 4096 * HID / 8);
  hipLaunchKernelGGL(f2bf_kernel, dim3(2048), dim3(256), 0, stream, wk, wbuf + (size_t)4096 * HID, 1024 * HID / 8);
  hipLaunchKernelGGL(f2bf_kernel, dim3(2048), dim3(256), 0, stream, wv, wbuf + (size_t)5120 * HID, 1024 * HID / 8);
  hipLaunchKernelGGL((gemm_nt<1>), dim3(16, 48), dim3(256), 0, stream,
                     hb, wbuf, bq, bk, bv, Qb, Kbuf, VTb, (float*)nullptr);
  hipLaunchKernelGGL(rope_apply, dim3(16384), dim3(256), 0, stream, Qb, cs, QSC, NH * S_LEN * 64);
  hipLaunchKernelGGL(rope_apply, dim3(4096), dim3(256), 0, stream, Kbuf, cs, 1.0f, NKV * S_LEN * 64);
  hipLaunchKernelGGL(attn_fwd, dim3(8, 32), dim3(512), 0, stream, Qb, Kbuf, VTb, attno);
  hipLaunchKernelGGL(f2bf_kernel, dim3(8192), dim3(256), 0, stream, wo, wbuf, 4096 * HID / 8);
  hipLaunchKernelGGL(gemm_op8, dim3(8, 32), dim3(512), 0, stream, attno, wbuf, out);
}

// Round 10
// 354.940 us; speedup vs baseline: 1.0836x; 1.0297x over previous
//
#include <hip/hip_runtime.h>
#include <hip/hip_bf16.h>

#define S_LEN 2048
#define HID 4096
#define NH 32
#define NKV 8
#define HD 128

typedef __attribute__((ext_vector_type(4))) float f32x4;
typedef __attribute__((ext_vector_type(8))) __bf16 bf16x8;
typedef __attribute__((ext_vector_type(8))) unsigned short u16x8;
typedef __attribute__((ext_vector_type(4))) unsigned short u16x4;

static __device__ __forceinline__ unsigned short f2bf(float x) {
  return __builtin_bit_cast(unsigned short, __float2bfloat16(x));
}
static __device__ __forceinline__ float bf2f(unsigned short u) {
  return __builtin_bit_cast(float, (unsigned int)u << 16);
}
static __device__ __forceinline__ void gld16(const unsigned short* g, unsigned short* l) {
  __builtin_amdgcn_global_load_lds(
      (const __attribute__((address_space(1))) unsigned int*)g,
      (__attribute__((address_space(3))) unsigned int*)l, 16, 0, 0);
}

// ---------------- fp32 -> bf16 bulk convert ----------------
__global__ void f2bf_kernel(const float* __restrict__ in, unsigned short* __restrict__ out, int n8) {
  int i = blockIdx.x * 256 + threadIdx.x;
  if (i >= n8) return;
  f32x4 a = ((const f32x4*)in)[(size_t)i * 2];
  f32x4 b = ((const f32x4*)in)[(size_t)i * 2 + 1];
  u16x8 w;
#pragma unroll
  for (int j = 0; j < 4; ++j) {
    w[j] = f2bf(a[j]);
    w[4 + j] = f2bf(b[j]);
  }
  ((u16x8*)out)[(size_t)i] = w;
}

// ---------------- RoPE table ----------------
__global__ void rope_table(float* cs) {
  int idx = blockIdx.x * blockDim.x + threadIdx.x;
  if (idx >= S_LEN * 64) return;
  int d = idx & 63;
  int p = idx >> 6;
  float invf = exp2f(-(float)d * (19.9315685693241741f / 64.0f));  // theta^-d/64
  float ang = (float)p * invf;
  cs[idx] = cosf(ang);
  cs[S_LEN * 64 + idx] = sinf(ang);
}

// ---------------- RoPE apply (in-place, bf16 [head][S][128], x scale) ----------------
__global__ void rope_apply(unsigned short* __restrict__ buf, const float* __restrict__ cs,
                           float scale, int total) {
  int idx = blockIdx.x * blockDim.x + threadIdx.x;
  if (idx >= total) return;  // total = nheads * S * 64
  int d = idx & 63;
  int hp = idx >> 6;
  int pos = hp & (S_LEN - 1);
  size_t base = (size_t)hp * HD;
  float c = cs[pos * 64 + d];
  float s = cs[S_LEN * 64 + pos * 64 + d];
  float x1 = bf2f(buf[base + d]);
  float x2 = bf2f(buf[base + 64 + d]);
  buf[base + d] = f2bf((x1 * c - x2 * s) * scale);
  buf[base + 64 + d] = f2bf((x2 * c + x1 * s) * scale);
}

// ---------------- QKV GEMM (EXACT round-2 m97 structure, 852 TF measured) ----------------
// 128x128 tile, BK=32, single LDS buffer, global_load_lds(16B), 2 barriers/K-step.
// All structural variants (dbuf R3, frag-remap R4, split-K R6, BK=64 R7) REGRESSED.
// MODE 1 only: fused QKV epilogue -> Qb/Kb (bf16 [head][S][128], +bias), VTb ([n][S], +bias)
template <int MODE>
__global__ __launch_bounds__(256) void gemm_nt(
    const unsigned short* __restrict__ A, const unsigned short* __restrict__ W,
    const float* __restrict__ bq, const float* __restrict__ bk, const float* __restrict__ bv,
    unsigned short* __restrict__ Qb, unsigned short* __restrict__ Kb,
    unsigned short* __restrict__ VTb, float* __restrict__ Cout) {
  __shared__ unsigned short As[4096];  // [128 rows][32] linear
  __shared__ unsigned short Bs[4096];
  int lin = blockIdx.x + 16 * blockIdx.y;
  int cpx = (16 * gridDim.y) >> 3;
  int swz = (lin & 7) * cpx + (lin >> 3);
  const int m0 = (swz & 15) * 128;
  const int n0 = (swz >> 4) * 128;
  const int tid = threadIdx.x, lane = tid & 63, wv = tid >> 6;
  const int wr = wv >> 1, wc = wv & 1;
  const int lr = lane & 15, lg = lane >> 4;
  const int srow = lane >> 2, skk = (lane & 3) * 8;

  const unsigned short* Ag0 = A + (size_t)(m0 + wv * 32 + srow) * HID + skk;
  const unsigned short* Ag1 = Ag0 + (size_t)16 * HID;
  const unsigned short* Wg0 = W + (size_t)(n0 + wv * 32 + srow) * HID + skk;
  const unsigned short* Wg1 = Wg0 + (size_t)16 * HID;
  unsigned short* Al0 = As + wv * 1024;  // wave-uniform LDS slice bases
  unsigned short* Al1 = As + wv * 1024 + 512;
  unsigned short* Bl0 = Bs + wv * 1024;
  unsigned short* Bl1 = Bs + wv * 1024 + 512;

  f32x4 acc[4][4] = {};

  for (int kt = 0; kt < HID / 32; ++kt) {
    const int ko = kt * 32;
    gld16(Ag0 + ko, Al0);
    gld16(Ag1 + ko, Al1);
    gld16(Wg0 + ko, Bl0);
    gld16(Wg1 + ko, Bl1);
    __syncthreads();  // drains vmcnt -> tile visible
    bf16x8 af[4], bfr[4];
#pragma unroll
    for (int i = 0; i < 4; ++i)
      af[i] = *(const bf16x8*)&As[(wr * 64 + i * 16 + lr) * 32 + lg * 8];
#pragma unroll
    for (int i = 0; i < 4; ++i)
      bfr[i] = *(const bf16x8*)&Bs[(wc * 64 + i * 16 + lr) * 32 + lg * 8];
#pragma unroll
    for (int mi = 0; mi < 4; ++mi)
#pragma unroll
      for (int ni = 0; ni < 4; ++ni)
        acc[mi][ni] = __builtin_amdgcn_mfma_f32_16x16x32_bf16(af[mi], bfr[ni], acc[mi][ni], 0, 0, 0);
    __syncthreads();  // reads done -> next stage may overwrite
  }

  {
    unsigned short* obuf;
    const float* bptr;
    int cbase;
    bool transp = false;
    if (n0 < 4096) { obuf = Qb; bptr = bq; cbase = n0; }
    else if (n0 < 5120) { obuf = Kb; bptr = bk; cbase = n0 - 4096; }
    else { obuf = VTb; bptr = bv; cbase = n0 - 5120; transp = true; }
#pragma unroll
    for (int ni = 0; ni < 4; ++ni) {
      int c = cbase + wc * 64 + ni * 16 + lr;
      float bb = bptr[c];
      if (!transp) {
        int head = c >> 7, d = c & 127;
#pragma unroll
        for (int mi = 0; mi < 4; ++mi) {
          int row = m0 + wr * 64 + mi * 16 + lg * 4;
#pragma unroll
          for (int j = 0; j < 4; ++j)
            obuf[((size_t)head * S_LEN + row + j) * HD + d] = f2bf(acc[mi][ni][j] + bb);
        }
      } else {
#pragma unroll
        for (int mi = 0; mi < 4; ++mi) {
          int row = m0 + wr * 64 + mi * 16 + lg * 4;
          u16x4 pk;
#pragma unroll
          for (int j = 0; j < 4; ++j) pk[j] = f2bf(acc[mi][ni][j] + bb);
          *(u16x4*)&obuf[(size_t)c * S_LEN + row] = pk;
        }
      }
    }
  }
}

// ---------------- Out-projection: depth-2 counted-vmcnt pipeline + T2 XOR swizzle ----------------
// C[2048][4096] fp32 = A[2048][4096]bf16 @ W[4096][4096]bf16^T.
// BM=256 x BN=128, grid 8x32 = 256 blocks = 1/CU, 8 waves as 4M x 2N (64x64/wave).
// LDS tiles now [rows][64] bf16 (128B rows) with T2 XOR swizzle (rule 21, both sides):
//   - gld16 dest LINEAR; per-lane GLOBAL source pre-swizzled: lane l sources slot
//     (l&7)^(l>>3) of its row -> LDS slot t of row r holds global slot t^(r&7).
//   - ds_read at slot (ks*4+lg)^(row&7) (row&7 == lr&7) -> returns global slot ks*4+lg.
//   8 consecutive lanes hit 8 distinct 16B slots -> conflict-free b128 reads
//   (old [rows][32] 64B-row layout was ~8-way conflicted = the LDS wall).
// Schedule identical to R9: STAGE(kt+2) -> vmcnt(12) -> barrier -> compute(kt) -> barrier.
__global__ __launch_bounds__(512) void gemm_op8(const unsigned short* __restrict__ A,
                                                const unsigned short* __restrict__ W,
                                                float* __restrict__ Cout) {
  __shared__ __align__(16) unsigned short Asl[3][256 * 64];  // 96 KB
  __shared__ __align__(16) unsigned short Bsl[3][128 * 64];  // 48 KB
  int lin = blockIdx.x + 8 * blockIdx.y;
  int swz = (lin & 7) * 32 + (lin >> 3);  // XCD-chunked
  const int m0 = (swz & 7) * 256;
  const int n0 = (swz >> 3) * 128;
  const int tid = threadIdx.x, lane = tid & 63, wv = tid >> 6;
  const int wr = wv >> 1, wc = wv & 1;  // 4M x 2N waves, per-wave 64x64
  const int lr = lane & 15, lg = lane >> 4;

  // staging: thread t covers row (t>>3) + round*64, sourcing swizzled slot (t&7)^((t>>3)&7)
  const int sslot = (tid & 7) ^ ((tid >> 3) & 7);
  const unsigned short* Ag = A + (size_t)(m0 + (tid >> 3)) * HID + sslot * 8;
  const unsigned short* Wg = W + (size_t)(n0 + (tid >> 3)) * HID + sslot * 8;

  f32x4 acc[4][4] = {};

  // one K64-tile stage: A 4 rounds of 64 rows + B 2 rounds = 6 gld16 (counts unchanged)
#define STAGE_OP(buf, kt)                                                     \
  {                                                                           \
    const int ko_ = (kt)*64;                                                  \
    gld16(Ag + ko_, &Asl[buf][wv * 512]);                                     \
    gld16(Ag + ko_ + (size_t)64 * HID, &Asl[buf][4096 + wv * 512]);           \
    gld16(Ag + ko_ + (size_t)128 * HID, &Asl[buf][8192 + wv * 512]);          \
    gld16(Ag + ko_ + (size_t)192 * HID, &Asl[buf][12288 + wv * 512]);         \
    gld16(Wg + ko_, &Bsl[buf][wv * 512]);                                     \
    gld16(Wg + ko_ + (size_t)64 * HID, &Bsl[buf][4096 + wv * 512]);           \
  }

  STAGE_OP(0, 0);
  STAGE_OP(1, 1);

  const int NT = HID / 64;  // 64
#pragma unroll 1
  for (int kt = 0; kt < NT; ++kt) {
    const int cur = kt % 3;
    if (kt + 2 < NT) {
      STAGE_OP((kt + 2) % 3, kt + 2);
      asm volatile("s_waitcnt vmcnt(12)" ::: "memory");  // tile kt landed; kt+1,kt+2 in flight
    } else if (kt + 1 < NT) {
      asm volatile("s_waitcnt vmcnt(6)" ::: "memory");
    } else {
      asm volatile("s_waitcnt vmcnt(0)" ::: "memory");
    }
    __builtin_amdgcn_s_barrier();  // buffer cur fully staged
#pragma unroll
    for (int ks = 0; ks < 2; ++ks) {
      bf16x8 af[4], bfr[4];
#pragma unroll
      for (int i = 0; i < 4; ++i) {
        int row = wr * 64 + i * 16 + lr;
        af[i] = *(const bf16x8*)&Asl[cur][row * 64 + (((ks * 4 + lg) ^ (lr & 7)) * 8)];
      }
#pragma unroll
      for (int i = 0; i < 4; ++i) {
        int row = wc * 64 + i * 16 + lr;
        bfr[i] = *(const bf16x8*)&Bsl[cur][row * 64 + (((ks * 4 + lg) ^ (lr & 7)) * 8)];
      }
#pragma unroll
      for (int mi = 0; mi < 4; ++mi)
#pragma unroll
        for (int ni = 0; ni < 4; ++ni)
          acc[mi][ni] = __builtin_amdgcn_mfma_f32_16x16x32_bf16(af[mi], bfr[ni], acc[mi][ni], 0, 0, 0);
    }
    __builtin_amdgcn_s_barrier();  // reads done -> buffer may be overwritten
  }
#undef STAGE_OP

#pragma unroll
  for (int mi = 0; mi < 4; ++mi) {
    int row = m0 + wr * 64 + mi * 16 + lg * 4;
#pragma unroll
    for (int ni = 0; ni < 4; ++ni) {
      int col = n0 + wc * 64 + ni * 16 + lr;
#pragma unroll
      for (int j = 0; j < 4; ++j)
        Cout[(size_t)(row + j) * HID + col] = acc[mi][ni][j];
    }
  }
}

// ---------------- Flash attention (unchanged from round 5) ----------------
__global__ __launch_bounds__(512) void attn_fwd(const unsigned short* __restrict__ Qb,
                                                const unsigned short* __restrict__ Kb,
                                                const unsigned short* __restrict__ VTb,
                                                unsigned short* __restrict__ Ob) {
  __shared__ unsigned short Kl[64][136];
  __shared__ unsigned short Vt[128][72];
  __shared__ unsigned short Pl[8][16][72];
  int lin = blockIdx.x + 8 * blockIdx.y;
  int swz = (lin & 7) * 32 + (lin >> 3);  // each XCD owns 4 q-heads = 1 kv-head
  const int pair = swz & 7;
  const int h = swz >> 3;
  const int kh = h >> 2;
  const int tid = threadIdx.x, lane = tid & 63, wv = tid >> 6;
  const int lr = lane & 15, lg = lane >> 4;
  const int krow = tid >> 4, koff = (tid & 15) * 8;   // K rows krow, krow+32
  const int vrow = tid >> 3, voff = (tid & 7) * 8;    // V rows vrow, vrow+64
  const unsigned short* Kbase = Kb + (size_t)kh * S_LEN * HD;
  const unsigned short* Vbase = VTb + (size_t)kh * HD * S_LEN;

  for (int half = 0; half < 2; ++half) {
    const int qt = half ? 15 - pair : pair;
    const int q0 = qt * 128;
    const int nt = 2 * qt + 2;
    bf16x8 qf[4];
    {
      const unsigned short* qp = Qb + ((size_t)h * S_LEN + q0 + wv * 16 + lr) * HD + lg * 8;
#pragma unroll
      for (int s = 0; s < 4; ++s) qf[s] = *(const bf16x8*)(qp + s * 32);
    }
    f32x4 o[8];
#pragma unroll
    for (int i = 0; i < 8; ++i) o[i] = f32x4{0.f, 0.f, 0.f, 0.f};
    float mrow[4] = {-1e30f, -1e30f, -1e30f, -1e30f};
    float lrow[4] = {0.f, 0.f, 0.f, 0.f};

    u16x8 kreg[2], vreg[2];
    {
      const unsigned short* kp = Kbase + (size_t)krow * HD + koff;
      const unsigned short* vp = Vbase + (size_t)vrow * S_LEN + voff;
      kreg[0] = *(const u16x8*)kp;
      kreg[1] = *(const u16x8*)(kp + (size_t)32 * HD);
      vreg[0] = *(const u16x8*)vp;
      vreg[1] = *(const u16x8*)(vp + (size_t)64 * S_LEN);
    }
    __syncthreads();  // prior half's LDS readers done
    *(u16x8*)&Kl[krow][koff] = kreg[0];
    *(u16x8*)&Kl[krow + 32][koff] = kreg[1];
    *(u16x8*)&Vt[vrow][voff] = vreg[0];
    *(u16x8*)&Vt[vrow + 64][voff] = vreg[1];
    __syncthreads();

    for (int t = 0; t < nt; ++t) {
      if (t + 1 < nt) {  // T14: prefetch next tile into regs
        const unsigned short* kp = Kbase + ((size_t)(t + 1) * 64 + krow) * HD + koff;
        const unsigned short* vp = Vbase + (size_t)vrow * S_LEN + (t + 1) * 64 + voff;
        kreg[0] = *(const u16x8*)kp;
        kreg[1] = *(const u16x8*)(kp + (size_t)32 * HD);
        vreg[0] = *(const u16x8*)vp;
        vreg[1] = *(const u16x8*)(vp + (size_t)64 * S_LEN);
      }
      const int c0 = t * 64;
      const bool active = (c0 <= q0 + wv * 16 + 15);  // wave-uniform: skip fully-masked
      if (active) {
        f32x4 sf[4];
        __builtin_amdgcn_s_setprio(1);
#pragma unroll
        for (int c = 0; c < 4; ++c) {
          f32x4 s = {0.f, 0.f, 0.f, 0.f};
#pragma unroll
          for (int ss = 0; ss < 4; ++ss) {
            bf16x8 kf = *(const bf16x8*)&Kl[c * 16 + lr][ss * 32 + lg * 8];
            s = __builtin_amdgcn_mfma_f32_16x16x32_bf16(qf[ss], kf, s, 0, 0, 0);
          }
          sf[c] = s;
        }
        __builtin_amdgcn_s_setprio(0);

        if (t >= 2 * qt) {  // diagonal tiles only
#pragma unroll
          for (int c = 0; c < 4; ++c)
#pragma unroll
            for (int j = 0; j < 4; ++j)
              if ((c0 + c * 16 + lr) > (q0 + wv * 16 + lg * 4 + j)) sf[c][j] = -1e30f;
        }
        float tmax[4] = {-1e30f, -1e30f, -1e30f, -1e30f};
#pragma unroll
        for (int c = 0; c < 4; ++c)
#pragma unroll
          for (int j = 0; j < 4; ++j) tmax[j] = fmaxf(tmax[j], sf[c][j]);
#pragma unroll
        for (int dlt = 1; dlt < 16; dlt <<= 1)
#pragma unroll
          for (int j = 0; j < 4; ++j)
            tmax[j] = fmaxf(tmax[j], __shfl_xor(tmax[j], dlt, 64));

        // T13 defer-max: only rescale when max grows materially
        bool need = (tmax[0] > mrow[0] + 8.f) || (tmax[1] > mrow[1] + 8.f) ||
                    (tmax[2] > mrow[2] + 8.f) || (tmax[3] > mrow[3] + 8.f);
        if (__any(need)) {
          float alpha[4];
#pragma unroll
          for (int j = 0; j < 4; ++j) {
            float mn = fmaxf(mrow[j], tmax[j]);
            alpha[j] = exp2f(mrow[j] - mn);
            mrow[j] = mn;
          }
#pragma unroll
          for (int f = 0; f < 8; ++f)
#pragma unroll
            for (int j = 0; j < 4; ++j) o[f][j] *= alpha[j];
#pragma unroll
          for (int j = 0; j < 4; ++j) lrow[j] *= alpha[j];
        }
        float tsum[4] = {0.f, 0.f, 0.f, 0.f};
#pragma unroll
        for (int c = 0; c < 4; ++c)
#pragma unroll
          for (int j = 0; j < 4; ++j) {
            float pv = exp2f(sf[c][j] - mrow[j]);
            tsum[j] += pv;
            Pl[wv][lg * 4 + j][(c * 16 + lr) ^ ((lg & 2) << 2)] = f2bf(pv);
          }
#pragma unroll
        for (int dlt = 1; dlt < 16; dlt <<= 1)
#pragma unroll
          for (int j = 0; j < 4; ++j) tsum[j] += __shfl_xor(tsum[j], dlt, 64);
#pragma unroll
        for (int j = 0; j < 4; ++j) lrow[j] += tsum[j];

        // PV
        __builtin_amdgcn_s_setprio(1);
#pragma unroll
        for (int ks = 0; ks < 2; ++ks) {
          bf16x8 pa = *(const bf16x8*)&Pl[wv][lr][(ks * 32 + lg * 8) ^ (lr & 8)];
#pragma unroll
          for (int df = 0; df < 8; ++df) {
            bf16x8 vb = *(const bf16x8*)&Vt[df * 16 + lr][ks * 32 + lg * 8];
            o[df] = __builtin_amdgcn_mfma_f32_16x16x32_bf16(pa, vb, o[df], 0, 0, 0);
          }
        }
        __builtin_amdgcn_s_setprio(0);
      }

      if (t + 1 < nt) {
        __syncthreads();  // all waves done reading current tile
        *(u16x8*)&Kl[krow][koff] = kreg[0];
        *(u16x8*)&Kl[krow + 32][koff] = kreg[1];
        *(u16x8*)&Vt[vrow][voff] = vreg[0];
        *(u16x8*)&Vt[vrow + 64][voff] = vreg[1];
        __syncthreads();
      }
    }

#pragma unroll
    for (int j = 0; j < 4; ++j) {
      float inv = 1.0f / lrow[j];
      int row = q0 + wv * 16 + lg * 4 + j;
#pragma unroll
      for (int df = 0; df < 8; ++df)
        Ob[(size_t)row * (NH * HD) + h * HD + df * 16 + lr] = f2bf(o[df][j] * inv);
    }
  }
}

// ---------------- launch ----------------
extern "C" void kernel_launch(void* const* d_in, const int* in_sizes, int n_in,
                              void* d_out, int out_size, void* d_ws, size_t ws_size,
                              hipStream_t stream) {
  const float* hidden = (const float*)d_in[0];
  const float* wq = (const float*)d_in[1];
  const float* bq = (const float*)d_in[2];
  const float* wk = (const float*)d_in[3];
  const float* bk = (const float*)d_in[4];
  const float* wv = (const float*)d_in[5];
  const float* bv = (const float*)d_in[6];
  const float* wo = (const float*)d_in[7];
  float* out = (float*)d_out;

  char* p = (char*)d_ws;
  float* cs = (float*)p;                      p += (size_t)1 << 20;
  unsigned short* hb = (unsigned short*)p;    p += (size_t)16 << 20;
  unsigned short* Qb = (unsigned short*)p;    p += (size_t)16 << 20;
  unsigned short* Kbuf = (unsigned short*)p;  p += (size_t)4 << 20;
  unsigned short* VTb = (unsigned short*)p;   p += (size_t)4 << 20;
  unsigned short* attno = (unsigned short*)p; p += (size_t)16 << 20;
  unsigned short* wbuf = (unsigned short*)p;  // 48 MB reused (qkv weights, then wo)

  const float QSC = 0.08838834764831845f * 1.44269504088896340f;  // 1/sqrt(128)*log2e

  hipLaunchKernelGGL(rope_table, dim3(512), dim3(256), 0, stream, cs);
  hipLaunchKernelGGL(f2bf_kernel, dim3(4096), dim3(256), 0, stream, hidden, hb, S_LEN * HID / 8);
  hipLaunchKernelGGL(f2bf_kernel, dim3(8192), dim3(256), 0, stream, wq, wbuf, 4096 * HID / 8);
  hipLaunchKernelGGL(f2bf_kernel, dim3(2048), dim3(256), 0, stream, wk, wbuf + (size_t)4096 * HID, 1024 * HID / 8);
  hipLaunchKernelGGL(f2bf_kernel, dim3(2048), dim3(256), 0, stream, wv, wbuf + (size_t)5120 * HID, 1024 * HID / 8);
  hipLaunchKernelGGL((gemm_nt<1>), dim3(16, 48), dim3(256), 0, stream,
                     hb, wbuf, bq, bk, bv, Qb, Kbuf, VTb, (float*)nullptr);
  hipLaunchKernelGGL(rope_apply, dim3(16384), dim3(256), 0, stream, Qb, cs, QSC, NH * S_LEN * 64);
  hipLaunchKernelGGL(rope_apply, dim3(4096), dim3(256), 0, stream, Kbuf, cs, 1.0f, NKV * S_LEN * 64);
  hipLaunchKernelGGL(attn_fwd, dim3(8, 32), dim3(512), 0, stream, Qb, Kbuf, VTb, attno);
  hipLaunchKernelGGL(f2bf_kernel, dim3(8192), dim3(256), 0, stream, wo, wbuf, 4096 * HID / 8);
  hipLaunchKernelGGL(gemm_op8, dim3(8, 32), dim3(512), 0, stream, attno, wbuf, out);
}

// Round 11
// 339.735 us; speedup vs baseline: 1.1321x; 1.0448x over previous
//
#include <hip/hip_runtime.h>
#include <hip/hip_bf16.h>

#define S_LEN 2048
#define HID 4096
#define NH 32
#define NKV 8
#define HD 128

typedef __attribute__((ext_vector_type(4))) float f32x4;
typedef __attribute__((ext_vector_type(8))) __bf16 bf16x8;
typedef __attribute__((ext_vector_type(8))) unsigned short u16x8;
typedef __attribute__((ext_vector_type(4))) unsigned short u16x4;

static __device__ __forceinline__ unsigned short f2bf(float x) {
  return __builtin_bit_cast(unsigned short, __float2bfloat16(x));
}
static __device__ __forceinline__ float bf2f(unsigned short u) {
  return __builtin_bit_cast(float, (unsigned int)u << 16);
}
static __device__ __forceinline__ void gld16(const unsigned short* g, unsigned short* l) {
  __builtin_amdgcn_global_load_lds(
      (const __attribute__((address_space(1))) unsigned int*)g,
      (__attribute__((address_space(3))) unsigned int*)l, 16, 0, 0);
}

// ---------------- fp32 -> bf16 bulk convert ----------------
__global__ void f2bf_kernel(const float* __restrict__ in, unsigned short* __restrict__ out, int n8) {
  int i = blockIdx.x * 256 + threadIdx.x;
  if (i >= n8) return;
  f32x4 a = ((const f32x4*)in)[(size_t)i * 2];
  f32x4 b = ((const f32x4*)in)[(size_t)i * 2 + 1];
  u16x8 w;
#pragma unroll
  for (int j = 0; j < 4; ++j) {
    w[j] = f2bf(a[j]);
    w[4 + j] = f2bf(b[j]);
  }
  ((u16x8*)out)[(size_t)i] = w;
}

// ---------------- fused wq/wk/wv fp32->bf16 (single launch) ----------------
// dest is contiguous: wq at 0 (2097152 x8), wk at +2097152, wv at +2621440
__global__ void f2bf_qkvw(const float* __restrict__ wq, const float* __restrict__ wk,
                          const float* __restrict__ wv, unsigned short* __restrict__ out) {
  int i = blockIdx.x * 256 + threadIdx.x;
  if (i >= 3145728) return;
  const float* src;
  size_t off;
  if (i < 2097152) { src = wq; off = i; }
  else if (i < 2621440) { src = wk; off = i - 2097152; }
  else { src = wv; off = i - 2621440; }
  f32x4 a = ((const f32x4*)src)[off * 2];
  f32x4 b = ((const f32x4*)src)[off * 2 + 1];
  u16x8 w;
#pragma unroll
  for (int j = 0; j < 4; ++j) {
    w[j] = f2bf(a[j]);
    w[4 + j] = f2bf(b[j]);
  }
  ((u16x8*)out)[(size_t)i] = w;
}

// ---------------- RoPE table ----------------
__global__ void rope_table(float* cs) {
  int idx = blockIdx.x * blockDim.x + threadIdx.x;
  if (idx >= S_LEN * 64) return;
  int d = idx & 63;
  int p = idx >> 6;
  float invf = exp2f(-(float)d * (19.9315685693241741f / 64.0f));  // theta^-d/64
  float ang = (float)p * invf;
  cs[idx] = cosf(ang);
  cs[S_LEN * 64 + idx] = sinf(ang);
}

// ---------------- fused RoPE apply for Q (scaled) and K (single launch) ----------------
__global__ void rope_apply_qk(unsigned short* __restrict__ Qb, unsigned short* __restrict__ Kbuf,
                              const float* __restrict__ cs, float qsc) {
  int idx = blockIdx.x * 256 + threadIdx.x;
  if (idx >= (NH + NKV) * S_LEN * 64) return;
  int d = idx & 63;
  int hp = idx >> 6;                 // combined head*S + pos, heads 0..39
  int pos = hp & (S_LEN - 1);
  int head = hp >> 11;
  unsigned short* buf;
  float scale;
  if (head < NH) { buf = Qb + (size_t)hp * HD; scale = qsc; }
  else { buf = Kbuf + (size_t)(hp - NH * S_LEN) * HD; scale = 1.0f; }
  float c = cs[pos * 64 + d];
  float s = cs[S_LEN * 64 + pos * 64 + d];
  float x1 = bf2f(buf[d]);
  float x2 = bf2f(buf[64 + d]);
  buf[d] = f2bf((x1 * c - x2 * s) * scale);
  buf[64 + d] = f2bf((x2 * c + x1 * s) * scale);
}

// ---------------- QKV GEMM (EXACT round-2 m97 structure, 852 TF measured) ----------------
// 128x128 tile, BK=32, single LDS buffer, global_load_lds(16B), 2 barriers/K-step.
// All structural variants (dbuf R3, frag-remap R4, split-K R6, BK=64 R7) REGRESSED.
// MODE 1 only: fused QKV epilogue -> Qb/Kb (bf16 [head][S][128], +bias), VTb ([n][S], +bias)
template <int MODE>
__global__ __launch_bounds__(256) void gemm_nt(
    const unsigned short* __restrict__ A, const unsigned short* __restrict__ W,
    const float* __restrict__ bq, const float* __restrict__ bk, const float* __restrict__ bv,
    unsigned short* __restrict__ Qb, unsigned short* __restrict__ Kb,
    unsigned short* __restrict__ VTb, float* __restrict__ Cout) {
  __shared__ unsigned short As[4096];  // [128 rows][32] linear
  __shared__ unsigned short Bs[4096];
  int lin = blockIdx.x + 16 * blockIdx.y;
  int cpx = (16 * gridDim.y) >> 3;
  int swz = (lin & 7) * cpx + (lin >> 3);
  const int m0 = (swz & 15) * 128;
  const int n0 = (swz >> 4) * 128;
  const int tid = threadIdx.x, lane = tid & 63, wv = tid >> 6;
  const int wr = wv >> 1, wc = wv & 1;
  const int lr = lane & 15, lg = lane >> 4;
  const int srow = lane >> 2, skk = (lane & 3) * 8;

  const unsigned short* Ag0 = A + (size_t)(m0 + wv * 32 + srow) * HID + skk;
  const unsigned short* Ag1 = Ag0 + (size_t)16 * HID;
  const unsigned short* Wg0 = W + (size_t)(n0 + wv * 32 + srow) * HID + skk;
  const unsigned short* Wg1 = Wg0 + (size_t)16 * HID;
  unsigned short* Al0 = As + wv * 1024;  // wave-uniform LDS slice bases
  unsigned short* Al1 = As + wv * 1024 + 512;
  unsigned short* Bl0 = Bs + wv * 1024;
  unsigned short* Bl1 = Bs + wv * 1024 + 512;

  f32x4 acc[4][4] = {};

  for (int kt = 0; kt < HID / 32; ++kt) {
    const int ko = kt * 32;
    gld16(Ag0 + ko, Al0);
    gld16(Ag1 + ko, Al1);
    gld16(Wg0 + ko, Bl0);
    gld16(Wg1 + ko, Bl1);
    __syncthreads();  // drains vmcnt -> tile visible
    bf16x8 af[4], bfr[4];
#pragma unroll
    for (int i = 0; i < 4; ++i)
      af[i] = *(const bf16x8*)&As[(wr * 64 + i * 16 + lr) * 32 + lg * 8];
#pragma unroll
    for (int i = 0; i < 4; ++i)
      bfr[i] = *(const bf16x8*)&Bs[(wc * 64 + i * 16 + lr) * 32 + lg * 8];
#pragma unroll
    for (int mi = 0; mi < 4; ++mi)
#pragma unroll
      for (int ni = 0; ni < 4; ++ni)
        acc[mi][ni] = __builtin_amdgcn_mfma_f32_16x16x32_bf16(af[mi], bfr[ni], acc[mi][ni], 0, 0, 0);
    __syncthreads();  // reads done -> next stage may overwrite
  }

  {
    unsigned short* obuf;
    const float* bptr;
    int cbase;
    bool transp = false;
    if (n0 < 4096) { obuf = Qb; bptr = bq; cbase = n0; }
    else if (n0 < 5120) { obuf = Kb; bptr = bk; cbase = n0 - 4096; }
    else { obuf = VTb; bptr = bv; cbase = n0 - 5120; transp = true; }
#pragma unroll
    for (int ni = 0; ni < 4; ++ni) {
      int c = cbase + wc * 64 + ni * 16 + lr;
      float bb = bptr[c];
      if (!transp) {
        int head = c >> 7, d = c & 127;
#pragma unroll
        for (int mi = 0; mi < 4; ++mi) {
          int row = m0 + wr * 64 + mi * 16 + lg * 4;
#pragma unroll
          for (int j = 0; j < 4; ++j)
            obuf[((size_t)head * S_LEN + row + j) * HD + d] = f2bf(acc[mi][ni][j] + bb);
        }
      } else {
#pragma unroll
        for (int mi = 0; mi < 4; ++mi) {
          int row = m0 + wr * 64 + mi * 16 + lg * 4;
          u16x4 pk;
#pragma unroll
          for (int j = 0; j < 4; ++j) pk[j] = f2bf(acc[mi][ni][j] + bb);
          *(u16x4*)&obuf[(size_t)c * S_LEN + row] = pk;
        }
      }
    }
  }
}

// ---------------- Out-projection: m201-style phase rhythm (T3+T4+T5 + T2 swizzle) ----------------
// C[2048][4096] fp32 = A[2048][4096]bf16 @ W[4096][4096]bf16^T.
// BM=256 x BN=128, grid 8x32 = 256 blocks = 1/CU, 8 waves as 4M x 2N (64x64/wave).
// Swizzled [rows][64] LDS identical to R10 (verified). NEW: each K64-tile split into
// 2 phases, each {8x ds_read (ks half) || 3x gld16 (tile kt+2) -> barrier ->
// lgkmcnt(0) -> setprio(1) -> 32 MFMA -> setprio(0) -> barrier}. 4 barriers/tile =
// m201's rhythm. vmcnt ledger: prologue stages t0,t1 + vmcnt(6)+barrier (t0 landed);
// steady-state vmcnt(6) in phase 1 (waits tile kt+1 issued a full iter ago; tile kt+2
// stays in flight -- NEVER drains to 0 mid-loop); tail vmcnt(0) once.
__global__ __launch_bounds__(512) void gemm_op8(const unsigned short* __restrict__ A,
                                                const unsigned short* __restrict__ W,
                                                float* __restrict__ Cout) {
  __shared__ __align__(16) unsigned short Asl[3][256 * 64];  // 96 KB
  __shared__ __align__(16) unsigned short Bsl[3][128 * 64];  // 48 KB
  int lin = blockIdx.x + 8 * blockIdx.y;
  int swz = (lin & 7) * 32 + (lin >> 3);  // XCD-chunked
  const int m0 = (swz & 7) * 256;
  const int n0 = (swz >> 3) * 128;
  const int tid = threadIdx.x, lane = tid & 63, wv = tid >> 6;
  const int wr = wv >> 1, wc = wv & 1;  // 4M x 2N waves, per-wave 64x64
  const int lr = lane & 15, lg = lane >> 4;

  // staging: thread t covers row (t>>3)+round*64, sourcing swizzled slot (t&7)^((t>>3)&7)
  const int sslot = (tid & 7) ^ ((tid >> 3) & 7);
  const unsigned short* Ag = A + (size_t)(m0 + (tid >> 3)) * HID + sslot * 8;
  const unsigned short* Wg = W + (size_t)(n0 + (tid >> 3)) * HID + sslot * 8;

  f32x4 acc[4][4] = {};

  // tile stage split 3+3 (A rows 0/64/128 ; A row 192 + B rows 0/64)
#define STAGE_A3(buf, kt)                                                     \
  {                                                                           \
    const int ko_ = (kt)*64;                                                  \
    gld16(Ag + ko_, &Asl[buf][wv * 512]);                                     \
    gld16(Ag + ko_ + (size_t)64 * HID, &Asl[buf][4096 + wv * 512]);           \
    gld16(Ag + ko_ + (size_t)128 * HID, &Asl[buf][8192 + wv * 512]);          \
  }
#define STAGE_B3(buf, kt)                                                     \
  {                                                                           \
    const int ko_ = (kt)*64;                                                  \
    gld16(Ag + ko_ + (size_t)192 * HID, &Asl[buf][12288 + wv * 512]);         \
    gld16(Wg + ko_, &Bsl[buf][wv * 512]);                                     \
    gld16(Wg + ko_ + (size_t)64 * HID, &Bsl[buf][4096 + wv * 512]);           \
  }

  STAGE_A3(0, 0); STAGE_B3(0, 0);
  STAGE_A3(1, 1); STAGE_B3(1, 1);
  asm volatile("s_waitcnt vmcnt(6)" ::: "memory");  // tile 0 landed (this wave)
  __builtin_amdgcn_s_barrier();                     // collective

  const int NT = HID / 64;  // 64
#pragma unroll 1
  for (int kt = 0; kt < NT; ++kt) {
    const int cur = kt % 3;
    const int nxt = (kt + 2) % 3;
    bf16x8 af[4], bfr[4];
    // ---- phase 0: ds_read ks=0 || stage first half of tile kt+2 || MFMA ks=0
#pragma unroll
    for (int i = 0; i < 4; ++i)
      af[i] = *(const bf16x8*)&Asl[cur][(wr * 64 + i * 16 + lr) * 64 + ((lg ^ (lr & 7)) * 8)];
#pragma unroll
    for (int i = 0; i < 4; ++i)
      bfr[i] = *(const bf16x8*)&Bsl[cur][(wc * 64 + i * 16 + lr) * 64 + ((lg ^ (lr & 7)) * 8)];
    if (kt + 2 < NT) STAGE_A3(nxt, kt + 2);
    __builtin_amdgcn_s_barrier();
    asm volatile("s_waitcnt lgkmcnt(0)" ::: "memory");
    __builtin_amdgcn_s_setprio(1);
#pragma unroll
    for (int mi = 0; mi < 4; ++mi)
#pragma unroll
      for (int ni = 0; ni < 4; ++ni)
        acc[mi][ni] = __builtin_amdgcn_mfma_f32_16x16x32_bf16(af[mi], bfr[ni], acc[mi][ni], 0, 0, 0);
    __builtin_amdgcn_s_setprio(0);
    __builtin_amdgcn_s_barrier();
    // ---- phase 1: ds_read ks=1 || stage second half || vmcnt(next-tile ready) || MFMA ks=1
#pragma unroll
    for (int i = 0; i < 4; ++i)
      af[i] = *(const bf16x8*)&Asl[cur][(wr * 64 + i * 16 + lr) * 64 + (((4 + lg) ^ (lr & 7)) * 8)];
#pragma unroll
    for (int i = 0; i < 4; ++i)
      bfr[i] = *(const bf16x8*)&Bsl[cur][(wc * 64 + i * 16 + lr) * 64 + (((4 + lg) ^ (lr & 7)) * 8)];
    if (kt + 2 < NT) {
      STAGE_B3(nxt, kt + 2);
      asm volatile("s_waitcnt vmcnt(6)" ::: "memory");  // tile kt+1 landed; kt+2 in flight
    } else if (kt + 1 < NT) {
      asm volatile("s_waitcnt vmcnt(0)" ::: "memory");  // tail: tile kt+1 landed
    }
    __builtin_amdgcn_s_barrier();
    asm volatile("s_waitcnt lgkmcnt(0)" ::: "memory");
    __builtin_amdgcn_s_setprio(1);
#pragma unroll
    for (int mi = 0; mi < 4; ++mi)
#pragma unroll
      for (int ni = 0; ni < 4; ++ni)
        acc[mi][ni] = __builtin_amdgcn_mfma_f32_16x16x32_bf16(af[mi], bfr[ni], acc[mi][ni], 0, 0, 0);
    __builtin_amdgcn_s_setprio(0);
    __builtin_amdgcn_s_barrier();
  }
#undef STAGE_A3
#undef STAGE_B3

#pragma unroll
  for (int mi = 0; mi < 4; ++mi) {
    int row = m0 + wr * 64 + mi * 16 + lg * 4;
#pragma unroll
    for (int ni = 0; ni < 4; ++ni) {
      int col = n0 + wc * 64 + ni * 16 + lr;
#pragma unroll
      for (int j = 0; j < 4; ++j)
        Cout[(size_t)(row + j) * HID + col] = acc[mi][ni][j];
    }
  }
}

// ---------------- Flash attention (unchanged from round 5) ----------------
__global__ __launch_bounds__(512) void attn_fwd(const unsigned short* __restrict__ Qb,
                                                const unsigned short* __restrict__ Kb,
                                                const unsigned short* __restrict__ VTb,
                                                unsigned short* __restrict__ Ob) {
  __shared__ unsigned short Kl[64][136];
  __shared__ unsigned short Vt[128][72];
  __shared__ unsigned short Pl[8][16][72];
  int lin = blockIdx.x + 8 * blockIdx.y;
  int swz = (lin & 7) * 32 + (lin >> 3);  // each XCD owns 4 q-heads = 1 kv-head
  const int pair = swz & 7;
  const int h = swz >> 3;
  const int kh = h >> 2;
  const int tid = threadIdx.x, lane = tid & 63, wv = tid >> 6;
  const int lr = lane & 15, lg = lane >> 4;
  const int krow = tid >> 4, koff = (tid & 15) * 8;   // K rows krow, krow+32
  const int vrow = tid >> 3, voff = (tid & 7) * 8;    // V rows vrow, vrow+64
  const unsigned short* Kbase = Kb + (size_t)kh * S_LEN * HD;
  const unsigned short* Vbase = VTb + (size_t)kh * HD * S_LEN;

  for (int half = 0; half < 2; ++half) {
    const int qt = half ? 15 - pair : pair;
    const int q0 = qt * 128;
    const int nt = 2 * qt + 2;
    bf16x8 qf[4];
    {
      const unsigned short* qp = Qb + ((size_t)h * S_LEN + q0 + wv * 16 + lr) * HD + lg * 8;
#pragma unroll
      for (int s = 0; s < 4; ++s) qf[s] = *(const bf16x8*)(qp + s * 32);
    }
    f32x4 o[8];
#pragma unroll
    for (int i = 0; i < 8; ++i) o[i] = f32x4{0.f, 0.f, 0.f, 0.f};
    float mrow[4] = {-1e30f, -1e30f, -1e30f, -1e30f};
    float lrow[4] = {0.f, 0.f, 0.f, 0.f};

    u16x8 kreg[2], vreg[2];
    {
      const unsigned short* kp = Kbase + (size_t)krow * HD + koff;
      const unsigned short* vp = Vbase + (size_t)vrow * S_LEN + voff;
      kreg[0] = *(const u16x8*)kp;
      kreg[1] = *(const u16x8*)(kp + (size_t)32 * HD);
      vreg[0] = *(const u16x8*)vp;
      vreg[1] = *(const u16x8*)(vp + (size_t)64 * S_LEN);
    }
    __syncthreads();  // prior half's LDS readers done
    *(u16x8*)&Kl[krow][koff] = kreg[0];
    *(u16x8*)&Kl[krow + 32][koff] = kreg[1];
    *(u16x8*)&Vt[vrow][voff] = vreg[0];
    *(u16x8*)&Vt[vrow + 64][voff] = vreg[1];
    __syncthreads();

    for (int t = 0; t < nt; ++t) {
      if (t + 1 < nt) {  // T14: prefetch next tile into regs
        const unsigned short* kp = Kbase + ((size_t)(t + 1) * 64 + krow) * HD + koff;
        const unsigned short* vp = Vbase + (size_t)vrow * S_LEN + (t + 1) * 64 + voff;
        kreg[0] = *(const u16x8*)kp;
        kreg[1] = *(const u16x8*)(kp + (size_t)32 * HD);
        vreg[0] = *(const u16x8*)vp;
        vreg[1] = *(const u16x8*)(vp + (size_t)64 * S_LEN);
      }
      const int c0 = t * 64;
      const bool active = (c0 <= q0 + wv * 16 + 15);  // wave-uniform: skip fully-masked
      if (active) {
        f32x4 sf[4];
        __builtin_amdgcn_s_setprio(1);
#pragma unroll
        for (int c = 0; c < 4; ++c) {
          f32x4 s = {0.f, 0.f, 0.f, 0.f};
#pragma unroll
          for (int ss = 0; ss < 4; ++ss) {
            bf16x8 kf = *(const bf16x8*)&Kl[c * 16 + lr][ss * 32 + lg * 8];
            s = __builtin_amdgcn_mfma_f32_16x16x32_bf16(qf[ss], kf, s, 0, 0, 0);
          }
          sf[c] = s;
        }
        __builtin_amdgcn_s_setprio(0);

        if (t >= 2 * qt) {  // diagonal tiles only
#pragma unroll
          for (int c = 0; c < 4; ++c)
#pragma unroll
            for (int j = 0; j < 4; ++j)
              if ((c0 + c * 16 + lr) > (q0 + wv * 16 + lg * 4 + j)) sf[c][j] = -1e30f;
        }
        float tmax[4] = {-1e30f, -1e30f, -1e30f, -1e30f};
#pragma unroll
        for (int c = 0; c < 4; ++c)
#pragma unroll
          for (int j = 0; j < 4; ++j) tmax[j] = fmaxf(tmax[j], sf[c][j]);
#pragma unroll
        for (int dlt = 1; dlt < 16; dlt <<= 1)
#pragma unroll
          for (int j = 0; j < 4; ++j)
            tmax[j] = fmaxf(tmax[j], __shfl_xor(tmax[j], dlt, 64));

        // T13 defer-max: only rescale when max grows materially
        bool need = (tmax[0] > mrow[0] + 8.f) || (tmax[1] > mrow[1] + 8.f) ||
                    (tmax[2] > mrow[2] + 8.f) || (tmax[3] > mrow[3] + 8.f);
        if (__any(need)) {
          float alpha[4];
#pragma unroll
          for (int j = 0; j < 4; ++j) {
            float mn = fmaxf(mrow[j], tmax[j]);
            alpha[j] = exp2f(mrow[j] - mn);
            mrow[j] = mn;
          }
#pragma unroll
          for (int f = 0; f < 8; ++f)
#pragma unroll
            for (int j = 0; j < 4; ++j) o[f][j] *= alpha[j];
#pragma unroll
          for (int j = 0; j < 4; ++j) lrow[j] *= alpha[j];
        }
        float tsum[4] = {0.f, 0.f, 0.f, 0.f};
#pragma unroll
        for (int c = 0; c < 4; ++c)
#pragma unroll
          for (int j = 0; j < 4; ++j) {
            float pv = exp2f(sf[c][j] - mrow[j]);
            tsum[j] += pv;
            Pl[wv][lg * 4 + j][(c * 16 + lr) ^ ((lg & 2) << 2)] = f2bf(pv);
          }
#pragma unroll
        for (int dlt = 1; dlt < 16; dlt <<= 1)
#pragma unroll
          for (int j = 0; j < 4; ++j) tsum[j] += __shfl_xor(tsum[j], dlt, 64);
#pragma unroll
        for (int j = 0; j < 4; ++j) lrow[j] += tsum[j];

        // PV
        __builtin_amdgcn_s_setprio(1);
#pragma unroll
        for (int ks = 0; ks < 2; ++ks) {
          bf16x8 pa = *(const bf16x8*)&Pl[wv][lr][(ks * 32 + lg * 8) ^ (lr & 8)];
#pragma unroll
          for (int df = 0; df < 8; ++df) {
            bf16x8 vb = *(const bf16x8*)&Vt[df * 16 + lr][ks * 32 + lg * 8];
            o[df] = __builtin_amdgcn_mfma_f32_16x16x32_bf16(pa, vb, o[df], 0, 0, 0);
          }
        }
        __builtin_amdgcn_s_setprio(0);
      }

      if (t + 1 < nt) {
        __syncthreads();  // all waves done reading current tile
        *(u16x8*)&Kl[krow][koff] = kreg[0];
        *(u16x8*)&Kl[krow + 32][koff] = kreg[1];
        *(u16x8*)&Vt[vrow][voff] = vreg[0];
        *(u16x8*)&Vt[vrow + 64][voff] = vreg[1];
        __syncthreads();
      }
    }

#pragma unroll
    for (int j = 0; j < 4; ++j) {
      float inv = 1.0f / lrow[j];
      int row = q0 + wv * 16 + lg * 4 + j;
#pragma unroll
      for (int df = 0; df < 8; ++df)
        Ob[(size_t)row * (NH * HD) + h * HD + df * 16 + lr] = f2bf(o[df][j] * inv);
    }
  }
}

// ---------------- launch ----------------
extern "C" void kernel_launch(void* const* d_in, const int* in_sizes, int n_in,
                              void* d_out, int out_size, void* d_ws, size_t ws_size,
                              hipStream_t stream) {
  const float* hidden = (const float*)d_in[0];
  const float* wq = (const float*)d_in[1];
  const float* bq = (const float*)d_in[2];
  const float* wk = (const float*)d_in[3];
  const float* bk = (const float*)d_in[4];
  const float* wv = (const float*)d_in[5];
  const float* bv = (const float*)d_in[6];
  const float* wo = (const float*)d_in[7];
  float* out = (float*)d_out;

  char* p = (char*)d_ws;
  float* cs = (float*)p;                      p += (size_t)1 << 20;
  unsigned short* hb = (unsigned short*)p;    p += (size_t)16 << 20;
  unsigned short* Qb = (unsigned short*)p;    p += (size_t)16 << 20;
  unsigned short* Kbuf = (unsigned short*)p;  p += (size_t)4 << 20;
  unsigned short* VTb = (unsigned short*)p;   p += (size_t)4 << 20;
  unsigned short* attno = (unsigned short*)p; p += (size_t)16 << 20;
  unsigned short* wbuf = (unsigned short*)p;  // 48 MB reused (qkv weights, then wo)

  const float QSC = 0.08838834764831845f * 1.44269504088896340f;  // 1/sqrt(128)*log2e

  hipLaunchKernelGGL(rope_table, dim3(512), dim3(256), 0, stream, cs);
  hipLaunchKernelGGL(f2bf_kernel, dim3(4096), dim3(256), 0, stream, hidden, hb, S_LEN * HID / 8);
  hipLaunchKernelGGL(f2bf_qkvw, dim3(12288), dim3(256), 0, stream, wq, wk, wv, wbuf);
  hipLaunchKernelGGL((gemm_nt<1>), dim3(16, 48), dim3(256), 0, stream,
                     hb, wbuf, bq, bk, bv, Qb, Kbuf, VTb, (float*)nullptr);
  hipLaunchKernelGGL(rope_apply_qk, dim3(20480), dim3(256), 0, stream, Qb, Kbuf, cs, QSC);
  hipLaunchKernelGGL(attn_fwd, dim3(8, 32), dim3(512), 0, stream, Qb, Kbuf, VTb, attno);
  hipLaunchKernelGGL(f2bf_kernel, dim3(8192), dim3(256), 0, stream, wo, wbuf, 4096 * HID / 8);
  hipLaunchKernelGGL(gemm_op8, dim3(8, 32), dim3(512), 0, stream, attno, wbuf, out);
}

// Round 12
// 329.779 us; speedup vs baseline: 1.1663x; 1.0302x over previous
//
#include <hip/hip_runtime.h>
#include <hip/hip_bf16.h>

#define S_LEN 2048
#define HID 4096
#define NH 32
#define NKV 8
#define HD 128

typedef __attribute__((ext_vector_type(4))) float f32x4;
typedef __attribute__((ext_vector_type(8))) __bf16 bf16x8;
typedef __attribute__((ext_vector_type(8))) unsigned short u16x8;
typedef __attribute__((ext_vector_type(4))) unsigned short u16x4;

static __device__ __forceinline__ unsigned short f2bf(float x) {
  return __builtin_bit_cast(unsigned short, __float2bfloat16(x));
}
static __device__ __forceinline__ float bf2f(unsigned short u) {
  return __builtin_bit_cast(float, (unsigned int)u << 16);
}
static __device__ __forceinline__ void gld16(const unsigned short* g, unsigned short* l) {
  __builtin_amdgcn_global_load_lds(
      (const __attribute__((address_space(1))) unsigned int*)g,
      (__attribute__((address_space(3))) unsigned int*)l, 16, 0, 0);
}
static __device__ __forceinline__ void cvt8(const float* src, size_t off8, unsigned short* dst) {
  f32x4 a = ((const f32x4*)src)[off8 * 2];
  f32x4 b = ((const f32x4*)src)[off8 * 2 + 1];
  u16x8 w;
#pragma unroll
  for (int j = 0; j < 4; ++j) {
    w[j] = f2bf(a[j]);
    w[4 + j] = f2bf(b[j]);
  }
  ((u16x8*)dst)[off8] = w;
}

// ---------------- fp32 -> bf16 bulk convert (fallback path for wo) ----------------
__global__ void f2bf_kernel(const float* __restrict__ in, unsigned short* __restrict__ out, int n8) {
  int i = blockIdx.x * 256 + threadIdx.x;
  if (i >= n8) return;
  cvt8(in, (size_t)i, out);
}

// ---------------- prep: hidden conv + qkv weight conv + rope table, ONE launch ----------------
// units: [0,1048576) hidden x8 ; [1048576, 4194304) qkvw x8 ; [4194304, 4325376) table elems
__global__ void prep_all(const float* __restrict__ hidden, const float* __restrict__ wq,
                         const float* __restrict__ wk, const float* __restrict__ wv,
                         unsigned short* __restrict__ hb, unsigned short* __restrict__ wbuf,
                         float* __restrict__ cs) {
  int i = blockIdx.x * 256 + threadIdx.x;
  if (i < 1048576) {
    cvt8(hidden, (size_t)i, hb);
  } else if (i < 4194304) {
    int j = i - 1048576;
    const float* src;
    size_t off;
    if (j < 2097152) { src = wq; off = j; }
    else if (j < 2621440) { src = wk; off = j - 2097152; }
    else { src = wv; off = j - 2621440; }
    f32x4 a = ((const f32x4*)src)[off * 2];
    f32x4 b = ((const f32x4*)src)[off * 2 + 1];
    u16x8 w;
#pragma unroll
    for (int jj = 0; jj < 4; ++jj) {
      w[jj] = f2bf(a[jj]);
      w[4 + jj] = f2bf(b[jj]);
    }
    ((u16x8*)wbuf)[(size_t)j] = w;
  } else {
    int idx = i - 4194304;
    if (idx < S_LEN * 64) {
      int d = idx & 63;
      int p = idx >> 6;
      float invf = exp2f(-(float)d * (19.9315685693241741f / 64.0f));  // theta^-d/64
      float ang = (float)p * invf;
      cs[idx] = cosf(ang);
      cs[S_LEN * 64 + idx] = sinf(ang);
    }
  }
}

// ---------------- RoPE apply, K only (in-place, bf16 [head][S][128]) ----------------
__global__ void rope_apply_k(unsigned short* __restrict__ buf, const float* __restrict__ cs) {
  int idx = blockIdx.x * 256 + threadIdx.x;
  if (idx >= NKV * S_LEN * 64) return;
  int d = idx & 63;
  int hp = idx >> 6;
  int pos = hp & (S_LEN - 1);
  size_t base = (size_t)hp * HD;
  float c = cs[pos * 64 + d];
  float s = cs[S_LEN * 64 + pos * 64 + d];
  float x1 = bf2f(buf[base + d]);
  float x2 = bf2f(buf[base + 64 + d]);
  buf[base + d] = f2bf(x1 * c - x2 * s);
  buf[base + 64 + d] = f2bf(x2 * c + x1 * s);
}

// ---------------- QKV GEMM (EXACT round-2 m97 structure, 852 TF measured) ----------------
// 128x128 tile, BK=32, single LDS buffer, global_load_lds(16B), 2 barriers/K-step.
// Main loop and epilogue UNCHANGED from R5-R11. NEW: optional grid-stride wo fp32->bf16
// tail (overlaps conversion with straggling GEMM blocks; HBM is 87% idle here).
// Q written WITHOUT rope (attn applies it on load now).
template <int MODE>
__global__ __launch_bounds__(256) void gemm_nt(
    const unsigned short* __restrict__ A, const unsigned short* __restrict__ W,
    const float* __restrict__ bq, const float* __restrict__ bk, const float* __restrict__ bv,
    unsigned short* __restrict__ Qb, unsigned short* __restrict__ Kb,
    unsigned short* __restrict__ VTb, const float* __restrict__ woSrc,
    unsigned short* __restrict__ woDst) {
  __shared__ unsigned short As[4096];  // [128 rows][32] linear
  __shared__ unsigned short Bs[4096];
  int lin = blockIdx.x + 16 * blockIdx.y;
  int cpx = (16 * gridDim.y) >> 3;
  int swz = (lin & 7) * cpx + (lin >> 3);
  const int m0 = (swz & 15) * 128;
  const int n0 = (swz >> 4) * 128;
  const int tid = threadIdx.x, lane = tid & 63, wv = tid >> 6;
  const int wr = wv >> 1, wc = wv & 1;
  const int lr = lane & 15, lg = lane >> 4;
  const int srow = lane >> 2, skk = (lane & 3) * 8;

  const unsigned short* Ag0 = A + (size_t)(m0 + wv * 32 + srow) * HID + skk;
  const unsigned short* Ag1 = Ag0 + (size_t)16 * HID;
  const unsigned short* Wg0 = W + (size_t)(n0 + wv * 32 + srow) * HID + skk;
  const unsigned short* Wg1 = Wg0 + (size_t)16 * HID;
  unsigned short* Al0 = As + wv * 1024;  // wave-uniform LDS slice bases
  unsigned short* Al1 = As + wv * 1024 + 512;
  unsigned short* Bl0 = Bs + wv * 1024;
  unsigned short* Bl1 = Bs + wv * 1024 + 512;

  f32x4 acc[4][4] = {};

  for (int kt = 0; kt < HID / 32; ++kt) {
    const int ko = kt * 32;
    gld16(Ag0 + ko, Al0);
    gld16(Ag1 + ko, Al1);
    gld16(Wg0 + ko, Bl0);
    gld16(Wg1 + ko, Bl1);
    __syncthreads();  // drains vmcnt -> tile visible
    bf16x8 af[4], bfr[4];
#pragma unroll
    for (int i = 0; i < 4; ++i)
      af[i] = *(const bf16x8*)&As[(wr * 64 + i * 16 + lr) * 32 + lg * 8];
#pragma unroll
    for (int i = 0; i < 4; ++i)
      bfr[i] = *(const bf16x8*)&Bs[(wc * 64 + i * 16 + lr) * 32 + lg * 8];
#pragma unroll
    for (int mi = 0; mi < 4; ++mi)
#pragma unroll
      for (int ni = 0; ni < 4; ++ni)
        acc[mi][ni] = __builtin_amdgcn_mfma_f32_16x16x32_bf16(af[mi], bfr[ni], acc[mi][ni], 0, 0, 0);
    __syncthreads();  // reads done -> next stage may overwrite
  }

  {
    unsigned short* obuf;
    const float* bptr;
    int cbase;
    bool transp = false;
    if (n0 < 4096) { obuf = Qb; bptr = bq; cbase = n0; }
    else if (n0 < 5120) { obuf = Kb; bptr = bk; cbase = n0 - 4096; }
    else { obuf = VTb; bptr = bv; cbase = n0 - 5120; transp = true; }
#pragma unroll
    for (int ni = 0; ni < 4; ++ni) {
      int c = cbase + wc * 64 + ni * 16 + lr;
      float bb = bptr[c];
      if (!transp) {
        int head = c >> 7, d = c & 127;
#pragma unroll
        for (int mi = 0; mi < 4; ++mi) {
          int row = m0 + wr * 64 + mi * 16 + lg * 4;
#pragma unroll
          for (int j = 0; j < 4; ++j)
            obuf[((size_t)head * S_LEN + row + j) * HD + d] = f2bf(acc[mi][ni][j] + bb);
        }
      } else {
#pragma unroll
        for (int mi = 0; mi < 4; ++mi) {
          int row = m0 + wr * 64 + mi * 16 + lg * 4;
          u16x4 pk;
#pragma unroll
          for (int j = 0; j < 4; ++j) pk[j] = f2bf(acc[mi][ni][j] + bb);
          *(u16x4*)&VTb[(size_t)c * S_LEN + row] = pk;
        }
      }
    }
  }

  // wo conversion tail: overlaps with GEMM blocks still running on other CUs
  if (MODE == 1 && woSrc) {
    const int nthr = 16 * 48 * 256;  // grid * block
    for (size_t i = (size_t)lin * 256 + tid; i < 2097152; i += nthr)
      cvt8(woSrc, i, woDst);
  }
}

// ---------------- Out-projection: phase rhythm + T2 swizzle (unchanged from R11) ----------------
__global__ __launch_bounds__(512) void gemm_op8(const unsigned short* __restrict__ A,
                                                const unsigned short* __restrict__ W,
                                                float* __restrict__ Cout) {
  __shared__ __align__(16) unsigned short Asl[3][256 * 64];  // 96 KB
  __shared__ __align__(16) unsigned short Bsl[3][128 * 64];  // 48 KB
  int lin = blockIdx.x + 8 * blockIdx.y;
  int swz = (lin & 7) * 32 + (lin >> 3);  // XCD-chunked
  const int m0 = (swz & 7) * 256;
  const int n0 = (swz >> 3) * 128;
  const int tid = threadIdx.x, lane = tid & 63, wv = tid >> 6;
  const int wr = wv >> 1, wc = wv & 1;  // 4M x 2N waves, per-wave 64x64
  const int lr = lane & 15, lg = lane >> 4;

  const int sslot = (tid & 7) ^ ((tid >> 3) & 7);
  const unsigned short* Ag = A + (size_t)(m0 + (tid >> 3)) * HID + sslot * 8;
  const unsigned short* Wg = W + (size_t)(n0 + (tid >> 3)) * HID + sslot * 8;

  f32x4 acc[4][4] = {};

#define STAGE_A3(buf, kt)                                                     \
  {                                                                           \
    const int ko_ = (kt)*64;                                                  \
    gld16(Ag + ko_, &Asl[buf][wv * 512]);                                     \
    gld16(Ag + ko_ + (size_t)64 * HID, &Asl[buf][4096 + wv * 512]);           \
    gld16(Ag + ko_ + (size_t)128 * HID, &Asl[buf][8192 + wv * 512]);          \
  }
#define STAGE_B3(buf, kt)                                                     \
  {                                                                           \
    const int ko_ = (kt)*64;                                                  \
    gld16(Ag + ko_ + (size_t)192 * HID, &Asl[buf][12288 + wv * 512]);         \
    gld16(Wg + ko_, &Bsl[buf][wv * 512]);                                     \
    gld16(Wg + ko_ + (size_t)64 * HID, &Bsl[buf][4096 + wv * 512]);           \
  }

  STAGE_A3(0, 0); STAGE_B3(0, 0);
  STAGE_A3(1, 1); STAGE_B3(1, 1);
  asm volatile("s_waitcnt vmcnt(6)" ::: "memory");
  __builtin_amdgcn_s_barrier();

  const int NT = HID / 64;  // 64
#pragma unroll 1
  for (int kt = 0; kt < NT; ++kt) {
    const int cur = kt % 3;
    const int nxt = (kt + 2) % 3;
    bf16x8 af[4], bfr[4];
    // ---- phase 0
#pragma unroll
    for (int i = 0; i < 4; ++i)
      af[i] = *(const bf16x8*)&Asl[cur][(wr * 64 + i * 16 + lr) * 64 + ((lg ^ (lr & 7)) * 8)];
#pragma unroll
    for (int i = 0; i < 4; ++i)
      bfr[i] = *(const bf16x8*)&Bsl[cur][(wc * 64 + i * 16 + lr) * 64 + ((lg ^ (lr & 7)) * 8)];
    if (kt + 2 < NT) STAGE_A3(nxt, kt + 2);
    __builtin_amdgcn_s_barrier();
    asm volatile("s_waitcnt lgkmcnt(0)" ::: "memory");
    __builtin_amdgcn_s_setprio(1);
#pragma unroll
    for (int mi = 0; mi < 4; ++mi)
#pragma unroll
      for (int ni = 0; ni < 4; ++ni)
        acc[mi][ni] = __builtin_amdgcn_mfma_f32_16x16x32_bf16(af[mi], bfr[ni], acc[mi][ni], 0, 0, 0);
    __builtin_amdgcn_s_setprio(0);
    __builtin_amdgcn_s_barrier();
    // ---- phase 1
#pragma unroll
    for (int i = 0; i < 4; ++i)
      af[i] = *(const bf16x8*)&Asl[cur][(wr * 64 + i * 16 + lr) * 64 + (((4 + lg) ^ (lr & 7)) * 8)];
#pragma unroll
    for (int i = 0; i < 4; ++i)
      bfr[i] = *(const bf16x8*)&Bsl[cur][(wc * 64 + i * 16 + lr) * 64 + (((4 + lg) ^ (lr & 7)) * 8)];
    if (kt + 2 < NT) {
      STAGE_B3(nxt, kt + 2);
      asm volatile("s_waitcnt vmcnt(6)" ::: "memory");
    } else if (kt + 1 < NT) {
      asm volatile("s_waitcnt vmcnt(0)" ::: "memory");
    }
    __builtin_amdgcn_s_barrier();
    asm volatile("s_waitcnt lgkmcnt(0)" ::: "memory");
    __builtin_amdgcn_s_setprio(1);
#pragma unroll
    for (int mi = 0; mi < 4; ++mi)
#pragma unroll
      for (int ni = 0; ni < 4; ++ni)
        acc[mi][ni] = __builtin_amdgcn_mfma_f32_16x16x32_bf16(af[mi], bfr[ni], acc[mi][ni], 0, 0, 0);
    __builtin_amdgcn_s_setprio(0);
    __builtin_amdgcn_s_barrier();
  }
#undef STAGE_A3
#undef STAGE_B3

#pragma unroll
  for (int mi = 0; mi < 4; ++mi) {
    int row = m0 + wr * 64 + mi * 16 + lg * 4;
#pragma unroll
    for (int ni = 0; ni < 4; ++ni) {
      int col = n0 + wc * 64 + ni * 16 + lr;
#pragma unroll
      for (int j = 0; j < 4; ++j)
        Cout[(size_t)(row + j) * HID + col] = acc[mi][ni][j];
    }
  }
}

// ---------------- Flash attention: R5 structure + fused Q-RoPE on load ----------------
__global__ __launch_bounds__(512) void attn_fwd(const unsigned short* __restrict__ Qb,
                                                const unsigned short* __restrict__ Kb,
                                                const unsigned short* __restrict__ VTb,
                                                const float* __restrict__ cs,
                                                unsigned short* __restrict__ Ob) {
  __shared__ unsigned short Kl[64][136];
  __shared__ unsigned short Vt[128][72];
  __shared__ unsigned short Pl[8][16][72];
  int lin = blockIdx.x + 8 * blockIdx.y;
  int swz = (lin & 7) * 32 + (lin >> 3);  // each XCD owns 4 q-heads = 1 kv-head
  const int pair = swz & 7;
  const int h = swz >> 3;
  const int kh = h >> 2;
  const int tid = threadIdx.x, lane = tid & 63, wv = tid >> 6;
  const int lr = lane & 15, lg = lane >> 4;
  const int krow = tid >> 4, koff = (tid & 15) * 8;   // K rows krow, krow+32
  const int vrow = tid >> 3, voff = (tid & 7) * 8;    // V rows vrow, vrow+64
  const unsigned short* Kbase = Kb + (size_t)kh * S_LEN * HD;
  const unsigned short* Vbase = VTb + (size_t)kh * HD * S_LEN;
  const float QSC = 0.08838834764831845f * 1.44269504088896340f;  // 1/sqrt(128)*log2e

  for (int half = 0; half < 2; ++half) {
    const int qt = half ? 15 - pair : pair;
    const int q0 = qt * 128;
    const int nt = 2 * qt + 2;
    // Q load + fused RoPE + scale. Pairing: frag s (d = lg*8+s*32) with s+2 (d+64).
    bf16x8 qf[4];
    {
      const unsigned short* qp = Qb + ((size_t)h * S_LEN + q0 + wv * 16 + lr) * HD + lg * 8;
      const int pos = q0 + wv * 16 + lr;
      u16x8 qr[4], qo[4];
#pragma unroll
      for (int s = 0; s < 4; ++s) qr[s] = *(const u16x8*)(qp + s * 32);
#pragma unroll
      for (int s = 0; s < 2; ++s) {
        const float* cc = cs + pos * 64 + s * 32 + lg * 8;
#pragma unroll
        for (int j = 0; j < 8; ++j) {
          float x1 = bf2f(qr[s][j]), x2 = bf2f(qr[s + 2][j]);
          float cv = cc[j], sv = cc[S_LEN * 64 + j];
          qo[s][j] = f2bf((x1 * cv - x2 * sv) * QSC);
          qo[s + 2][j] = f2bf((x2 * cv + x1 * sv) * QSC);
        }
      }
#pragma unroll
      for (int s = 0; s < 4; ++s) qf[s] = __builtin_bit_cast(bf16x8, qo[s]);
    }
    f32x4 o[8];
#pragma unroll
    for (int i = 0; i < 8; ++i) o[i] = f32x4{0.f, 0.f, 0.f, 0.f};
    float mrow[4] = {-1e30f, -1e30f, -1e30f, -1e30f};
    float lrow[4] = {0.f, 0.f, 0.f, 0.f};

    u16x8 kreg[2], vreg[2];
    {
      const unsigned short* kp = Kbase + (size_t)krow * HD + koff;
      const unsigned short* vp = Vbase + (size_t)vrow * S_LEN + voff;
      kreg[0] = *(const u16x8*)kp;
      kreg[1] = *(const u16x8*)(kp + (size_t)32 * HD);
      vreg[0] = *(const u16x8*)vp;
      vreg[1] = *(const u16x8*)(vp + (size_t)64 * S_LEN);
    }
    __syncthreads();  // prior half's LDS readers done
    *(u16x8*)&Kl[krow][koff] = kreg[0];
    *(u16x8*)&Kl[krow + 32][koff] = kreg[1];
    *(u16x8*)&Vt[vrow][voff] = vreg[0];
    *(u16x8*)&Vt[vrow + 64][voff] = vreg[1];
    __syncthreads();

    for (int t = 0; t < nt; ++t) {
      if (t + 1 < nt) {  // T14: prefetch next tile into regs
        const unsigned short* kp = Kbase + ((size_t)(t + 1) * 64 + krow) * HD + koff;
        const unsigned short* vp = Vbase + (size_t)vrow * S_LEN + (t + 1) * 64 + voff;
        kreg[0] = *(const u16x8*)kp;
        kreg[1] = *(const u16x8*)(kp + (size_t)32 * HD);
        vreg[0] = *(const u16x8*)vp;
        vreg[1] = *(const u16x8*)(vp + (size_t)64 * S_LEN);
      }
      const int c0 = t * 64;
      const bool active = (c0 <= q0 + wv * 16 + 15);  // wave-uniform: skip fully-masked
      if (active) {
        f32x4 sf[4];
        __builtin_amdgcn_s_setprio(1);
#pragma unroll
        for (int c = 0; c < 4; ++c) {
          f32x4 s = {0.f, 0.f, 0.f, 0.f};
#pragma unroll
          for (int ss = 0; ss < 4; ++ss) {
            bf16x8 kf = *(const bf16x8*)&Kl[c * 16 + lr][ss * 32 + lg * 8];
            s = __builtin_amdgcn_mfma_f32_16x16x32_bf16(qf[ss], kf, s, 0, 0, 0);
          }
          sf[c] = s;
        }
        __builtin_amdgcn_s_setprio(0);

        if (t >= 2 * qt) {  // diagonal tiles only
#pragma unroll
          for (int c = 0; c < 4; ++c)
#pragma unroll
            for (int j = 0; j < 4; ++j)
              if ((c0 + c * 16 + lr) > (q0 + wv * 16 + lg * 4 + j)) sf[c][j] = -1e30f;
        }
        float tmax[4] = {-1e30f, -1e30f, -1e30f, -1e30f};
#pragma unroll
        for (int c = 0; c < 4; ++c)
#pragma unroll
          for (int j = 0; j < 4; ++j) tmax[j] = fmaxf(tmax[j], sf[c][j]);
#pragma unroll
        for (int dlt = 1; dlt < 16; dlt <<= 1)
#pragma unroll
          for (int j = 0; j < 4; ++j)
            tmax[j] = fmaxf(tmax[j], __shfl_xor(tmax[j], dlt, 64));

        // T13 defer-max: only rescale when max grows materially
        bool need = (tmax[0] > mrow[0] + 8.f) || (tmax[1] > mrow[1] + 8.f) ||
                    (tmax[2] > mrow[2] + 8.f) || (tmax[3] > mrow[3] + 8.f);
        if (__any(need)) {
          float alpha[4];
#pragma unroll
          for (int j = 0; j < 4; ++j) {
            float mn = fmaxf(mrow[j], tmax[j]);
            alpha[j] = exp2f(mrow[j] - mn);
            mrow[j] = mn;
          }
#pragma unroll
          for (int f = 0; f < 8; ++f)
#pragma unroll
            for (int j = 0; j < 4; ++j) o[f][j] *= alpha[j];
#pragma unroll
          for (int j = 0; j < 4; ++j) lrow[j] *= alpha[j];
        }
        float tsum[4] = {0.f, 0.f, 0.f, 0.f};
#pragma unroll
        for (int c = 0; c < 4; ++c)
#pragma unroll
          for (int j = 0; j < 4; ++j) {
            float pv = exp2f(sf[c][j] - mrow[j]);
            tsum[j] += pv;
            Pl[wv][lg * 4 + j][(c * 16 + lr) ^ ((lg & 2) << 2)] = f2bf(pv);
          }
#pragma unroll
        for (int dlt = 1; dlt < 16; dlt <<= 1)
#pragma unroll
          for (int j = 0; j < 4; ++j) tsum[j] += __shfl_xor(tsum[j], dlt, 64);
#pragma unroll
        for (int j = 0; j < 4; ++j) lrow[j] += tsum[j];

        // PV
        __builtin_amdgcn_s_setprio(1);
#pragma unroll
        for (int ks = 0; ks < 2; ++ks) {
          bf16x8 pa = *(const bf16x8*)&Pl[wv][lr][(ks * 32 + lg * 8) ^ (lr & 8)];
#pragma unroll
          for (int df = 0; df < 8; ++df) {
            bf16x8 vb = *(const bf16x8*)&Vt[df * 16 + lr][ks * 32 + lg * 8];
            o[df] = __builtin_amdgcn_mfma_f32_16x16x32_bf16(pa, vb, o[df], 0, 0, 0);
          }
        }
        __builtin_amdgcn_s_setprio(0);
      }

      if (t + 1 < nt) {
        __syncthreads();  // all waves done reading current tile
        *(u16x8*)&Kl[krow][koff] = kreg[0];
        *(u16x8*)&Kl[krow + 32][koff] = kreg[1];
        *(u16x8*)&Vt[vrow][voff] = vreg[0];
        *(u16x8*)&Vt[vrow + 64][voff] = vreg[1];
        __syncthreads();
      }
    }

#pragma unroll
    for (int j = 0; j < 4; ++j) {
      float inv = 1.0f / lrow[j];
      int row = q0 + wv * 16 + lg * 4 + j;
#pragma unroll
      for (int df = 0; df < 8; ++df)
        Ob[(size_t)row * (NH * HD) + h * HD + df * 16 + lr] = f2bf(o[df][j] * inv);
    }
  }
}

// ---------------- launch ----------------
extern "C" void kernel_launch(void* const* d_in, const int* in_sizes, int n_in,
                              void* d_out, int out_size, void* d_ws, size_t ws_size,
                              hipStream_t stream) {
  const float* hidden = (const float*)d_in[0];
  const float* wq = (const float*)d_in[1];
  const float* bq = (const float*)d_in[2];
  const float* wk = (const float*)d_in[3];
  const float* bk = (const float*)d_in[4];
  const float* wv = (const float*)d_in[5];
  const float* bv = (const float*)d_in[6];
  const float* wo = (const float*)d_in[7];
  float* out = (float*)d_out;

  char* p = (char*)d_ws;
  float* cs = (float*)p;                      p += (size_t)1 << 20;
  unsigned short* hb = (unsigned short*)p;    p += (size_t)16 << 20;
  unsigned short* Qb = (unsigned short*)p;    p += (size_t)16 << 20;
  unsigned short* Kbuf = (unsigned short*)p;  p += (size_t)4 << 20;
  unsigned short* VTb = (unsigned short*)p;   p += (size_t)4 << 20;
  unsigned short* attno = (unsigned short*)p; p += (size_t)16 << 20;
  unsigned short* wbuf = (unsigned short*)p;  p += (size_t)6144 * HID * 2;  // 50.3 MB qkv weights
  unsigned short* wo_sep = (unsigned short*)p;                               // +33.5 MB if ws allows

  const size_t NEED = ((size_t)57 << 20) + (size_t)6144 * HID * 2 + (size_t)HID * HID * 2;
  const bool fits = ws_size >= NEED;

  hipLaunchKernelGGL(prep_all, dim3(16896), dim3(256), 0, stream, hidden, wq, wk, wv, hb, wbuf, cs);
  hipLaunchKernelGGL((gemm_nt<1>), dim3(16, 48), dim3(256), 0, stream,
                     hb, wbuf, bq, bk, bv, Qb, Kbuf, VTb,
                     fits ? wo : (const float*)nullptr, fits ? wo_sep : (unsigned short*)nullptr);
  hipLaunchKernelGGL(rope_apply_k, dim3(4096), dim3(256), 0, stream, Kbuf, cs);
  hipLaunchKernelGGL(attn_fwd, dim3(8, 32), dim3(512), 0, stream, Qb, Kbuf, VTb, cs, attno);
  unsigned short* wo_bf;
  if (fits) {
    wo_bf = wo_sep;  // converted inside gemm_nt tail, overlapped
  } else {
    wo_bf = wbuf;    // fallback: qkv weights dead after gemm -> reuse region
    hipLaunchKernelGGL(f2bf_kernel, dim3(8192), dim3(256), 0, stream, wo, wbuf, HID * HID / 8);
  }
  hipLaunchKernelGGL(gemm_op8, dim3(8, 32), dim3(512), 0, stream, attno, wo_bf, out);
}